// Round 5
// baseline (559.412 us; speedup 1.0000x reference)
//
#include <hip/hip_runtime.h>
#include <math.h>

#define MSTR 136   // LDS row stride (shorts) for proj/node staging
#define FSTR 264   // node-kernel f stride

typedef __attribute__((ext_vector_type(8))) short short8;
typedef __attribute__((ext_vector_type(4))) float f32x4;

__device__ __forceinline__ unsigned short f2bf(float x) {
    unsigned int u = __float_as_uint(x);
    u += 0x7fffu + ((u >> 16) & 1u);   // round-to-nearest-even
    return (unsigned short)(u >> 16);
}
__device__ __forceinline__ float bf2f(short v) {
    return __uint_as_float(((unsigned int)(unsigned short)v) << 16);
}
__device__ __forceinline__ float fsilu(float x) {
    return x * (1.0f / (1.0f + __expf(-x)));
}
__device__ __forceinline__ float fsigm(float x) {
    return 1.0f / (1.0f + __expf(-x));
}
__device__ __forceinline__ void atomAddF(float* p, float v) {
    unsafeAtomicAdd(p, v);   // hardware global_atomic_add_f32
}

// ---------------------------------------------------------------------------
// Kernel A: weight transpose (fp32 [K][128] -> bf16 [128][K]) + dst histogram
// ---------------------------------------------------------------------------
struct PrepArgs { const float* src[10]; };

__global__ __launch_bounds__(256) void prep_hist_kernel(PrepArgs pa, short* __restrict__ wsb,
                                                        const int* __restrict__ lld,
                                                        const int* __restrict__ kld,
                                                        int* __restrict__ hist) {
    int idx = blockIdx.x * 256 + threadIdx.x;
    if (idx < 245760) {
        int pair = idx / 49152;
        int rem  = idx - pair * 49152;
        int second = (rem >= 32768) ? 1 : 0;
        int mi = pair * 2 + second;
        int within = second ? (rem - 32768) : rem;
        int n, k, K;
        if (second) { K = 128; n = within >> 7; k = within & 127; }
        else        { K = 256; n = within >> 8; k = within & 255; }
        int dstoff = pair * 49152 + second * 32768;
        wsb[dstoff + n * K + k] = (short)f2bf(pa.src[mi][k * 128 + n]);
        return;
    }
    idx -= 245760;
    if (idx < 320000) { atomicAdd(&hist[lld[idx]], 1); return; }
    idx -= 320000;
    if (idx < 160000) atomicAdd(&hist[10000 + kld[idx]], 1);
}

// ---------------------------------------------------------------------------
// Kernel B: blocks 0-1 = exclusive scan (10000 bins each); blocks 2.. = proj
// GEMMs (independent of the sort chain -> overlaps the narrow scan).
// ---------------------------------------------------------------------------
struct ProjDesc { const float* A; const short* Bt; short* out; const float* bias;
                  int rows; int ktb; int co; int hasb; };
struct SPArgs {
    const int* hist; int* cursor;
    ProjDesc d[8];
};

__global__ __launch_bounds__(256) void scan_proj_kernel(SPArgs sp) {
    __shared__ __align__(16) char smem[41024];
    const int t = threadIdx.x;
    if (blockIdx.x < 2) {
        int* bins = (int*)smem;
        int* ps   = (int*)(smem + 40000);
        const int b = blockIdx.x;
        const int* h = sp.hist + b * 10000;
        int* cur = sp.cursor + b * 10000;
        for (int i = t; i < 10000; i += 256) bins[i] = h[i];
        __syncthreads();
        const int base = t * 40;
        int s = 0;
#pragma unroll 8
        for (int i = 0; i < 40; i++) { int ii = base + i; if (ii < 10000) s += bins[ii]; }
        ps[t] = s;
        __syncthreads();
        for (int off = 1; off < 256; off <<= 1) {
            int v = (t >= off) ? ps[t - off] : 0;
            __syncthreads();
            ps[t] += v;
            __syncthreads();
        }
        int run = ps[t] - s;
        for (int i = 0; i < 40; i++) {
            int ii = base + i;
            if (ii < 10000) { int c = bins[ii]; bins[ii] = run; run += c; }
        }
        __syncthreads();
        for (int i = t; i < 10000; i += 256) cur[i] = bins[i];
        return;
    }
    // ---- projection part ----
    short* a_lds = (short*)smem;
    const int pb = blockIdx.x - 2;
    const int di = pb / 157, tile = pb - di * 157;
    const ProjDesc pd = sp.d[di];
    if (tile * 64 >= pd.rows) return;
    {
        const int r = t >> 2, q = t & 3;
        const int node = tile * 64 + r;
        short* arow = a_lds + r * MSTR + q * 32;
        if (node < pd.rows) {
            const float* ap = pd.A + (size_t)node * 128 + q * 32;
#pragma unroll
            for (int i = 0; i < 4; i++) {
                float4 v0 = *(const float4*)(ap + i * 8);
                float4 v1 = *(const float4*)(ap + i * 8 + 4);
                short8 o;
                o[0] = (short)f2bf(v0.x); o[1] = (short)f2bf(v0.y);
                o[2] = (short)f2bf(v0.z); o[3] = (short)f2bf(v0.w);
                o[4] = (short)f2bf(v1.x); o[5] = (short)f2bf(v1.y);
                o[6] = (short)f2bf(v1.z); o[7] = (short)f2bf(v1.w);
                *(short8*)(arow + i * 8) = o;
            }
        } else {
            short8 z = {0, 0, 0, 0, 0, 0, 0, 0};
#pragma unroll
            for (int i = 0; i < 4; i++) *(short8*)(arow + i * 8) = z;
        }
    }
    __syncthreads();

    const int ln = t & 63, wv = t >> 6;
    const int lrow = ln & 15, quad = ln >> 4;
    const int c0 = wv * 32 + lrow, c1 = c0 + 16;

    short8 bf0[4], bf1[4];
#pragma unroll
    for (int kt = 0; kt < 4; kt++) {
        bf0[kt] = *(const short8*)(pd.Bt + c0 * 256 + (pd.ktb + kt) * 32 + quad * 8);
        bf1[kt] = *(const short8*)(pd.Bt + c1 * 256 + (pd.ktb + kt) * 32 + quad * 8);
    }
    const float bb0 = pd.hasb ? pd.bias[c0] : 0.0f;
    const float bb1 = pd.hasb ? pd.bias[c1] : 0.0f;
#pragma unroll
    for (int mt = 0; mt < 4; mt++) {
        short8 af[4];
#pragma unroll
        for (int kt = 0; kt < 4; kt++)
            af[kt] = *(const short8*)(&a_lds[(mt * 16 + lrow) * MSTR + kt * 32 + quad * 8]);
        f32x4 a0 = {0.f, 0.f, 0.f, 0.f}, a1 = {0.f, 0.f, 0.f, 0.f};
#pragma unroll
        for (int kt = 0; kt < 4; kt++) {
            a0 = __builtin_amdgcn_mfma_f32_16x16x32_bf16(af[kt], bf0[kt], a0, 0, 0, 0);
            a1 = __builtin_amdgcn_mfma_f32_16x16x32_bf16(af[kt], bf1[kt], a1, 0, 0, 0);
        }
#pragma unroll
        for (int r = 0; r < 4; r++) {
            const int node = tile * 64 + mt * 16 + quad * 4 + r;
            if (node < pd.rows) {
                pd.out[(size_t)node * 256 + pd.co + c0] = (short)f2bf(a0[r] + bb0);
                pd.out[(size_t)node * 256 + pd.co + c1] = (short)f2bf(a1[r] + bb1);
            }
        }
    }
}

// ---------------------------------------------------------------------------
// Kernel C: scatter edges into dst-sorted order
// ---------------------------------------------------------------------------
__global__ __launch_bounds__(256) void scatter_kernel(const int* __restrict__ lls,
                                                      const int* __restrict__ lld,
                                                      const int* __restrict__ kls,
                                                      const int* __restrict__ kld,
                                                      int* __restrict__ cursor,
                                                      int* __restrict__ ll_ssrc, int* __restrict__ ll_sdst,
                                                      int* __restrict__ kl_ssrc, int* __restrict__ kl_sdst) {
    int i = blockIdx.x * 256 + threadIdx.x;
    if (i < 320000) {
        int d = lld[i];
        int p = atomicAdd(&cursor[d], 1);
        ll_ssrc[p] = lls[i]; ll_sdst[p] = d;
    } else if (i < 480000) {
        int j = i - 320000;
        int d = kld[j];
        int p = atomicAdd(&cursor[10000 + d], 1);
        kl_ssrc[p] = kls[j]; kl_sdst[p] = d;
    }
}

// ---------------------------------------------------------------------------
// Edge kernel: wave-local, barrier-free, zero LDS. Each wave owns 16 sorted
// edges. A-fragments (mh/mc) computed directly in registers: lane(lrow,quad)
// holds A[m=lrow][k=kt*32+quad*8+j]. GEMM2 loops 8 n-tiles of W2t (L1-hot).
// D[row=quad*4+r (edge)][col=16n+lrow]; gate/sv via shfl butterflies; atomics
// flushed with wave-uniform fast path when all 16 dsts equal.
// ---------------------------------------------------------------------------
struct EdgeSet {
    const short *Ps, *Pd;        // [nodes][256] bf16: 0..127 e-proj, 128..255 c-proj (b1 in Pd)
    const float *xs, *xd;
    const int *esrc, *edst;      // dst-sorted
    const float *w256e, *w256c;  // dij coefficient rows (fp32)
    const short *W2t, *cW2t;     // [128][128] bf16 [col][k]
    const float *b2e, *b2c;
    const float *aW, *ab, *cW3;
};
struct EdgePair { EdgeSet s[2]; int llwaves; };

__global__ __launch_bounds__(256) void edge_kernel(EdgePair ep,
                                                   float* __restrict__ hne,
                                                   float* __restrict__ xne)
{
    const int t = threadIdx.x;
    const int wv = t >> 6, ln = t & 63;
    const int lrow = ln & 15, quad = ln >> 4;
    const int gw = blockIdx.x * 4 + wv;
    const int isKL = (gw >= ep.llwaves) ? 1 : 0;
    const EdgeSet P = ep.s[isKL];
    const int ew = (isKL ? gw - ep.llwaves : gw) * 16;

    // per-lane edge (A-row / xdf owner): e = ew + lrow
    const int me = ew + lrow;
    const int s = P.esrc[me], d = P.edst[me];
    const float dx = P.xs[s * 3 + 0] - P.xd[d * 3 + 0];
    const float dy = P.xs[s * 3 + 1] - P.xd[d * 3 + 1];
    const float dz = P.xs[s * 3 + 2] - P.xd[d * 3 + 2];
    const float dd = sqrtf(dx * dx + dy * dy + dz * dz);
    const float inv = 1.0f / (dd + 1.0f);
    const float xdf0 = dx * inv, xdf1 = dy * inv, xdf2 = dz * inv;

    const int dfirst = P.edst[ew], dlast = P.edst[ew + 15];
    const bool uni = (dfirst == dlast);
    int d_r[4];
#pragma unroll
    for (int r = 0; r < 4; r++) d_r[r] = P.edst[ew + quad * 4 + r];

    const int kbase = quad * 8;

    // ================= c path: sv = (silu(mc@cW2+b2c)) @ cW3 =================
    float sv0, sv1, sv2, sv3;
    {
        short8 af[4];
        const short* ps = P.Ps + (size_t)s * 256 + 128;
        const short* pq = P.Pd + (size_t)d * 256 + 128;
#pragma unroll
        for (int kt = 0; kt < 4; kt++) {
            const int k = kt * 32 + kbase;
            short8 a = *(const short8*)(ps + k);
            short8 b = *(const short8*)(pq + k);
            float4 wA = *(const float4*)(P.w256c + k);
            float4 wB = *(const float4*)(P.w256c + k + 4);
            short8 o;
            o[0] = (short)f2bf(fsilu(bf2f(a[0]) + bf2f(b[0]) + dd * wA.x));
            o[1] = (short)f2bf(fsilu(bf2f(a[1]) + bf2f(b[1]) + dd * wA.y));
            o[2] = (short)f2bf(fsilu(bf2f(a[2]) + bf2f(b[2]) + dd * wA.z));
            o[3] = (short)f2bf(fsilu(bf2f(a[3]) + bf2f(b[3]) + dd * wA.w));
            o[4] = (short)f2bf(fsilu(bf2f(a[4]) + bf2f(b[4]) + dd * wB.x));
            o[5] = (short)f2bf(fsilu(bf2f(a[5]) + bf2f(b[5]) + dd * wB.y));
            o[6] = (short)f2bf(fsilu(bf2f(a[6]) + bf2f(b[6]) + dd * wB.z));
            o[7] = (short)f2bf(fsilu(bf2f(a[7]) + bf2f(b[7]) + dd * wB.w));
            af[kt] = o;
        }
        float gp0 = 0.f, gp1 = 0.f, gp2 = 0.f, gp3 = 0.f;
#pragma unroll
        for (int n = 0; n < 8; n++) {
            const int col = n * 16 + lrow;
            short8 bf[4];
#pragma unroll
            for (int kt = 0; kt < 4; kt++)
                bf[kt] = *(const short8*)(P.cW2t + col * 128 + kt * 32 + kbase);
            f32x4 acc = {0.f, 0.f, 0.f, 0.f};
#pragma unroll
            for (int kt = 0; kt < 4; kt++)
                acc = __builtin_amdgcn_mfma_f32_16x16x32_bf16(af[kt], bf[kt], acc, 0, 0, 0);
            const float bb = P.b2c[col], w3 = P.cW3[col];
            gp0 += fsilu(acc[0] + bb) * w3;
            gp1 += fsilu(acc[1] + bb) * w3;
            gp2 += fsilu(acc[2] + bb) * w3;
            gp3 += fsilu(acc[3] + bb) * w3;
        }
#pragma unroll
        for (int m = 1; m < 16; m <<= 1) {
            gp0 += __shfl_xor(gp0, m, 64);
            gp1 += __shfl_xor(gp1, m, 64);
            gp2 += __shfl_xor(gp2, m, 64);
            gp3 += __shfl_xor(gp3, m, 64);
        }
        sv0 = gp0; sv1 = gp1; sv2 = gp2; sv3 = gp3;
    }
    // ---- x scatter: broadcast sv of edge lrow to this lane, reduce, flush ----
    {
        const int srcl = (lrow >> 2) * 16;
        float s0 = __shfl(sv0, srcl, 64), s1 = __shfl(sv1, srcl, 64);
        float s2 = __shfl(sv2, srcl, 64), s3 = __shfl(sv3, srcl, 64);
        const int j = lrow & 3;
        const float sve = (j == 0) ? s0 : ((j == 1) ? s1 : ((j == 2) ? s2 : s3));
        float vx0 = sve * xdf0, vx1 = sve * xdf1, vx2 = sve * xdf2;
        if (uni) {
#pragma unroll
            for (int m = 1; m < 16; m <<= 1) {
                vx0 += __shfl_xor(vx0, m, 64);
                vx1 += __shfl_xor(vx1, m, 64);
                vx2 += __shfl_xor(vx2, m, 64);
            }
            if (ln == 0) {
                atomAddF(&xne[dfirst * 3 + 0], vx0);
                atomAddF(&xne[dfirst * 3 + 1], vx1);
                atomAddF(&xne[dfirst * 3 + 2], vx2);
            }
        } else if (ln < 16) {
            atomAddF(&xne[d * 3 + 0], vx0);
            atomAddF(&xne[d * 3 + 1], vx1);
            atomAddF(&xne[d * 3 + 2], vx2);
        }
    }

    // ================= h path: msg = silu(mh@W2+b2e) * gate ==================
    {
        short8 af[4];
        const short* ps = P.Ps + (size_t)s * 256;
        const short* pq = P.Pd + (size_t)d * 256;
#pragma unroll
        for (int kt = 0; kt < 4; kt++) {
            const int k = kt * 32 + kbase;
            short8 a = *(const short8*)(ps + k);
            short8 b = *(const short8*)(pq + k);
            float4 wA = *(const float4*)(P.w256e + k);
            float4 wB = *(const float4*)(P.w256e + k + 4);
            short8 o;
            o[0] = (short)f2bf(fsilu(bf2f(a[0]) + bf2f(b[0]) + dd * wA.x));
            o[1] = (short)f2bf(fsilu(bf2f(a[1]) + bf2f(b[1]) + dd * wA.y));
            o[2] = (short)f2bf(fsilu(bf2f(a[2]) + bf2f(b[2]) + dd * wA.z));
            o[3] = (short)f2bf(fsilu(bf2f(a[3]) + bf2f(b[3]) + dd * wA.w));
            o[4] = (short)f2bf(fsilu(bf2f(a[4]) + bf2f(b[4]) + dd * wB.x));
            o[5] = (short)f2bf(fsilu(bf2f(a[5]) + bf2f(b[5]) + dd * wB.y));
            o[6] = (short)f2bf(fsilu(bf2f(a[6]) + bf2f(b[6]) + dd * wB.z));
            o[7] = (short)f2bf(fsilu(bf2f(a[7]) + bf2f(b[7]) + dd * wB.w));
            af[kt] = o;
        }
        float m2[8][4];
        float gp0 = 0.f, gp1 = 0.f, gp2 = 0.f, gp3 = 0.f;
#pragma unroll
        for (int n = 0; n < 8; n++) {
            const int col = n * 16 + lrow;
            short8 bf[4];
#pragma unroll
            for (int kt = 0; kt < 4; kt++)
                bf[kt] = *(const short8*)(P.W2t + col * 128 + kt * 32 + kbase);
            f32x4 acc = {0.f, 0.f, 0.f, 0.f};
#pragma unroll
            for (int kt = 0; kt < 4; kt++)
                acc = __builtin_amdgcn_mfma_f32_16x16x32_bf16(af[kt], bf[kt], acc, 0, 0, 0);
            const float bb = P.b2e[col], aw = P.aW[col];
#pragma unroll
            for (int r = 0; r < 4; r++) {
                float v = fsilu(acc[r] + bb);
                m2[n][r] = v;
            }
            gp0 += m2[n][0] * aw; gp1 += m2[n][1] * aw;
            gp2 += m2[n][2] * aw; gp3 += m2[n][3] * aw;
        }
        const float abv = P.ab[0];
#pragma unroll
        for (int m = 1; m < 16; m <<= 1) {
            gp0 += __shfl_xor(gp0, m, 64);
            gp1 += __shfl_xor(gp1, m, 64);
            gp2 += __shfl_xor(gp2, m, 64);
            gp3 += __shfl_xor(gp3, m, 64);
        }
        float gate[4];
        gate[0] = fsigm(gp0 + abv); gate[1] = fsigm(gp1 + abv);
        gate[2] = fsigm(gp2 + abv); gate[3] = fsigm(gp3 + abv);

        if (uni) {
            const size_t drow = (size_t)dfirst * 128;
#pragma unroll
            for (int n = 0; n < 8; n++) {
                float ssum = m2[n][0] * gate[0] + m2[n][1] * gate[1]
                           + m2[n][2] * gate[2] + m2[n][3] * gate[3];
                ssum += __shfl_xor(ssum, 16, 64);
                ssum += __shfl_xor(ssum, 32, 64);
                if (quad == 0) atomAddF(&hne[drow + n * 16 + lrow], ssum);
            }
        } else {
#pragma unroll
            for (int n = 0; n < 8; n++) {
                const int col = n * 16 + lrow;
                int cur = d_r[0];
                float acc2 = m2[n][0] * gate[0];
#pragma unroll
                for (int r = 1; r < 4; r++) {
                    float v = m2[n][r] * gate[r];
                    if (d_r[r] == cur) acc2 += v;
                    else {
                        atomAddF(&hne[(size_t)cur * 128 + col], acc2);
                        cur = d_r[r]; acc2 = v;
                    }
                }
                atomAddF(&hne[(size_t)cur * 128 + col], acc2);
            }
        }
    }
}

// ---------------------------------------------------------------------------
// Node kernel (unchanged)
// ---------------------------------------------------------------------------
__global__ __launch_bounds__(256) void node_kernel(
    const float* __restrict__ h_lig, const float* __restrict__ zlig,
    const short* __restrict__ W1t, const float* __restrict__ b1v,
    const short* __restrict__ W2t, const float* __restrict__ b2v,
    const float* __restrict__ x_lig,
    float* __restrict__ acc_h, float* __restrict__ acc_x)
{
    __shared__ __align__(16) short f_lds[64 * FSTR];
    __shared__ __align__(16) short m_lds[64 * MSTR];
    const int t = threadIdx.x;
    const int nb = blockIdx.x * 64;

    {
        const int e = t >> 2, q = t & 3;
        const int node = nb + e;
        short* frow = &f_lds[e * FSTR + q * 32];
        if (node < 10000) {
            const float zi = 1.0f / zlig[node];
            const float4* hp = (const float4*)(h_lig + (size_t)node * 128 + q * 32);
            const float4* np = (const float4*)(acc_h + (size_t)node * 128 + q * 32);
#pragma unroll
            for (int i = 0; i < 8; i++) {
                float4 v = hp[i];
                *(ushort4*)(frow + i * 4) =
                    make_ushort4(f2bf(v.x), f2bf(v.y), f2bf(v.z), f2bf(v.w));
            }
#pragma unroll
            for (int i = 0; i < 8; i++) {
                float4 v = np[i];
                *(ushort4*)(frow + 128 + i * 4) =
                    make_ushort4(f2bf(v.x * zi), f2bf(v.y * zi), f2bf(v.z * zi), f2bf(v.w * zi));
            }
        } else {
            const ushort4 zz = make_ushort4(0, 0, 0, 0);
#pragma unroll
            for (int i = 0; i < 8; i++) {
                *(ushort4*)(frow + i * 4) = zz;
                *(ushort4*)(frow + 128 + i * 4) = zz;
            }
        }
    }
    __syncthreads();

    const int ln = t & 63, wv = t >> 6;
    const int lrow = ln & 15, quad = ln >> 4;
    const int c0 = wv * 32 + lrow, c1 = c0 + 16;

    {
        short8 bf0[8], bf1[8];
#pragma unroll
        for (int kt = 0; kt < 8; kt++) {
            bf0[kt] = *(const short8*)(W1t + c0 * 256 + kt * 32 + quad * 8);
            bf1[kt] = *(const short8*)(W1t + c1 * 256 + kt * 32 + quad * 8);
        }
        const float bb0 = b1v[c0], bb1 = b1v[c1];
#pragma unroll
        for (int mt = 0; mt < 4; mt++) {
            short8 af[8];
#pragma unroll
            for (int kt = 0; kt < 8; kt++)
                af[kt] = *(const short8*)(&f_lds[(mt * 16 + lrow) * FSTR + kt * 32 + quad * 8]);
            f32x4 a0 = {0.f, 0.f, 0.f, 0.f}, a1 = {0.f, 0.f, 0.f, 0.f};
#pragma unroll
            for (int kt = 0; kt < 8; kt++) {
                a0 = __builtin_amdgcn_mfma_f32_16x16x32_bf16(af[kt], bf0[kt], a0, 0, 0, 0);
                a1 = __builtin_amdgcn_mfma_f32_16x16x32_bf16(af[kt], bf1[kt], a1, 0, 0, 0);
            }
#pragma unroll
            for (int r = 0; r < 4; r++) {
                const int erow = mt * 16 + quad * 4 + r;
                m_lds[erow * MSTR + c0] = (short)f2bf(fsilu(a0[r] + bb0));
                m_lds[erow * MSTR + c1] = (short)f2bf(fsilu(a1[r] + bb1));
            }
        }
    }
    __syncthreads();

    {
        short8 bf0[4], bf1[4];
#pragma unroll
        for (int kt = 0; kt < 4; kt++) {
            bf0[kt] = *(const short8*)(W2t + c0 * 128 + kt * 32 + quad * 8);
            bf1[kt] = *(const short8*)(W2t + c1 * 128 + kt * 32 + quad * 8);
        }
        const float bb0 = b2v[c0], bb1 = b2v[c1];
#pragma unroll
        for (int mt = 0; mt < 4; mt++) {
            short8 af[4];
#pragma unroll
            for (int kt = 0; kt < 4; kt++)
                af[kt] = *(const short8*)(&m_lds[(mt * 16 + lrow) * MSTR + kt * 32 + quad * 8]);
            f32x4 a0 = {0.f, 0.f, 0.f, 0.f}, a1 = {0.f, 0.f, 0.f, 0.f};
#pragma unroll
            for (int kt = 0; kt < 4; kt++) {
                a0 = __builtin_amdgcn_mfma_f32_16x16x32_bf16(af[kt], bf0[kt], a0, 0, 0, 0);
                a1 = __builtin_amdgcn_mfma_f32_16x16x32_bf16(af[kt], bf1[kt], a1, 0, 0, 0);
            }
#pragma unroll
            for (int r = 0; r < 4; r++) {
                const int node = nb + mt * 16 + quad * 4 + r;
                if (node < 10000) {
                    acc_h[(size_t)node * 128 + c0] = a0[r] + bb0 + h_lig[(size_t)node * 128 + c0];
                    acc_h[(size_t)node * 128 + c1] = a1[r] + bb1 + h_lig[(size_t)node * 128 + c1];
                }
            }
        }
    }
    if (t < 64) {
        const int node = nb + t;
        if (node < 10000) {
            const float zi = 1.0f / zlig[node];
#pragma unroll
            for (int i = 0; i < 3; i++)
                acc_x[node * 3 + i] = x_lig[node * 3 + i] + acc_x[node * 3 + i] * zi;
        }
    }
}

extern "C" void kernel_launch(void* const* d_in, const int* in_sizes, int n_in,
                              void* d_out, int out_size, void* d_ws, size_t ws_size,
                              hipStream_t stream)
{
    (void)in_sizes; (void)n_in; (void)ws_size;
    const float* h_lig  = (const float*)d_in[0];
    const float* h_kp   = (const float*)d_in[1];
    const float* x_lig  = (const float*)d_in[2];
    const float* x_kp   = (const float*)d_in[3];
    const float* z_lig  = (const float*)d_in[4];
    const float* ll_eW1 = (const float*)d_in[5];
    const float* ll_eb1 = (const float*)d_in[6];
    const float* ll_eW2 = (const float*)d_in[7];
    const float* ll_eb2 = (const float*)d_in[8];
    const float* ll_aW  = (const float*)d_in[9];
    const float* ll_ab  = (const float*)d_in[10];
    const float* ll_cW1 = (const float*)d_in[11];
    const float* ll_cb1 = (const float*)d_in[12];
    const float* ll_cW2 = (const float*)d_in[13];
    const float* ll_cb2 = (const float*)d_in[14];
    const float* ll_cW3 = (const float*)d_in[15];
    const float* kl_eW1 = (const float*)d_in[16];
    const float* kl_eb1 = (const float*)d_in[17];
    const float* kl_eW2 = (const float*)d_in[18];
    const float* kl_eb2 = (const float*)d_in[19];
    const float* kl_aW  = (const float*)d_in[20];
    const float* kl_ab  = (const float*)d_in[21];
    const float* kl_cW1 = (const float*)d_in[22];
    const float* kl_cb1 = (const float*)d_in[23];
    const float* kl_cW2 = (const float*)d_in[24];
    const float* kl_cb2 = (const float*)d_in[25];
    const float* kl_cW3 = (const float*)d_in[26];
    const float* n_W1   = (const float*)d_in[27];
    const float* n_b1   = (const float*)d_in[28];
    const float* n_W2   = (const float*)d_in[29];
    const float* n_b2   = (const float*)d_in[30];
    const int* ll_src = (const int*)d_in[31];
    const int* ll_dst = (const int*)d_in[32];
    const int* kl_src = (const int*)d_in[33];
    const int* kl_dst = (const int*)d_in[34];

    float* out = (float*)d_out;
    float* hne = out;                 // [10000,128]
    float* xne = out + 1280000;       // [10000,3]

    // ws layout (bytes) — ~20.9 MB
    char* wsc = (char*)d_ws;
    short* wsb    = (short*)wsc;                 //       0: weights (491,520 B)
    short* P_ll_s = (short*)(wsc +   491520);    // 5,120,000 B  [10000][256]
    short* P_ll_d = (short*)(wsc +  5611520);    // 5,120,000 B
    short* P_kl_s = (short*)(wsc + 10731520);    // 1,024,000 B  [2000][256]
    short* P_kl_d = (short*)(wsc + 11755520);    // 5,120,000 B
    int* ll_ssrc  = (int*)(wsc + 16875520);      // 1,280,000 B
    int* ll_sdst  = (int*)(wsc + 18155520);      // 1,280,000 B
    int* kl_ssrc  = (int*)(wsc + 19435520);      //   640,000 B
    int* kl_sdst  = (int*)(wsc + 20075520);      //   640,000 B
    int* hist     = (int*)(wsc + 20715520);      //    80,000 B (20000 ints)
    int* cursor   = (int*)(wsc + 20795520);      //    80,000 B -> end 20,875,520

    hipMemsetAsync(d_out, 0, (size_t)out_size * sizeof(float), stream);
    hipMemsetAsync(hist, 0, 80000, stream);

    // A. weight transpose + histogram
    {
        PrepArgs pa;
        pa.src[0] = ll_eW1; pa.src[1] = ll_eW2; pa.src[2] = ll_cW1; pa.src[3] = ll_cW2;
        pa.src[4] = kl_eW1; pa.src[5] = kl_eW2; pa.src[6] = kl_cW1; pa.src[7] = kl_cW2;
        pa.src[8] = n_W1;   pa.src[9] = n_W2;
        prep_hist_kernel<<<2835, 256, 0, stream>>>(pa, wsb, ll_dst, kl_dst, hist);
    }
    // B. scan (2 blocks) + projections (independent, overlap)
    {
        SPArgs sp;
        sp.hist = hist; sp.cursor = cursor;
        sp.d[0] = { h_lig, wsb + 0,      P_ll_s, ll_eb1, 10000, 0, 0,   0 };
        sp.d[1] = { h_lig, wsb + 49152,  P_ll_s, ll_cb1, 10000, 0, 128, 0 };
        sp.d[2] = { h_lig, wsb + 0,      P_ll_d, ll_eb1, 10000, 4, 0,   1 };
        sp.d[3] = { h_lig, wsb + 49152,  P_ll_d, ll_cb1, 10000, 4, 128, 1 };
        sp.d[4] = { h_kp,  wsb + 98304,  P_kl_s, kl_eb1,  2000, 0, 0,   0 };
        sp.d[5] = { h_kp,  wsb + 147456, P_kl_s, kl_cb1,  2000, 0, 128, 0 };
        sp.d[6] = { h_lig, wsb + 98304,  P_kl_d, kl_eb1, 10000, 4, 0,   1 };
        sp.d[7] = { h_lig, wsb + 147456, P_kl_d, kl_cb1, 10000, 4, 128, 1 };
        scan_proj_kernel<<<2 + 8 * 157, 256, 0, stream>>>(sp);
    }
    // C. scatter into sorted order
    scatter_kernel<<<1875, 256, 0, stream>>>(ll_src, ll_dst, kl_src, kl_dst, cursor,
                                             ll_ssrc, ll_sdst, kl_ssrc, kl_sdst);
    // D. edges: 30000 waves (20000 ll + 10000 kl), 4 waves/block
    {
        EdgePair ep;
        ep.llwaves = 20000;
        ep.s[0] = { P_ll_s, P_ll_d, x_lig, x_lig, ll_ssrc, ll_sdst,
                    ll_eW1 + 256 * 128, ll_cW1 + 256 * 128,
                    wsb + 32768, wsb + 81920, ll_eb2, ll_cb2,
                    ll_aW, ll_ab, ll_cW3 };
        ep.s[1] = { P_kl_s, P_kl_d, x_kp, x_lig, kl_ssrc, kl_sdst,
                    kl_eW1 + 256 * 128, kl_cW1 + 256 * 128,
                    wsb + 131072, wsb + 180224, kl_eb2, kl_cb2,
                    kl_aW, kl_ab, kl_cW3 };
        edge_kernel<<<7500, 256, 0, stream>>>(ep, hne, xne);
    }
    // E. node MLP + final outputs
    node_kernel<<<157, 256, 0, stream>>>(
        h_lig, z_lig, wsb + 196608, n_b1, wsb + 229376, n_b2,
        x_lig, hne, xne);
}

// Round 6
// 427.412 us; speedup vs baseline: 1.3088x; 1.3088x over previous
//
#include <hip/hip_runtime.h>
#include <math.h>

#define EPB  32    // edges per block
#define MSTR 136   // m LDS row stride (shorts): 128 + 8 pad
#define FSTR 264   // node-kernel f stride

typedef __attribute__((ext_vector_type(8))) short short8;
typedef __attribute__((ext_vector_type(4))) float f32x4;

__device__ __forceinline__ unsigned short f2bf(float x) {
    unsigned int u = __float_as_uint(x);
    u += 0x7fffu + ((u >> 16) & 1u);   // round-to-nearest-even
    return (unsigned short)(u >> 16);
}
__device__ __forceinline__ float bf2f(short v) {
    return __uint_as_float(((unsigned int)(unsigned short)v) << 16);
}
__device__ __forceinline__ float fsilu(float x) {
    return x * (1.0f / (1.0f + __expf(-x)));
}
__device__ __forceinline__ float fsigm(float x) {
    return 1.0f / (1.0f + __expf(-x));
}
__device__ __forceinline__ void atomAddF(float* p, float v) {
    unsafeAtomicAdd(p, v);   // hardware global_atomic_add_f32
}

// ---------------------------------------------------------------------------
// Kernel A: weight transpose (fp32 [K][128] -> bf16 [128][K]) + dst histogram
// ---------------------------------------------------------------------------
struct PrepArgs { const float* src[10]; };

__global__ __launch_bounds__(256) void prep_hist_kernel(PrepArgs pa, short* __restrict__ wsb,
                                                        const int* __restrict__ lld,
                                                        const int* __restrict__ kld,
                                                        int* __restrict__ hist) {
    int idx = blockIdx.x * 256 + threadIdx.x;
    if (idx < 245760) {
        int pair = idx / 49152;
        int rem  = idx - pair * 49152;
        int second = (rem >= 32768) ? 1 : 0;
        int mi = pair * 2 + second;
        int within = second ? (rem - 32768) : rem;
        int n, k, K;
        if (second) { K = 128; n = within >> 7; k = within & 127; }
        else        { K = 256; n = within >> 8; k = within & 255; }
        int dstoff = pair * 49152 + second * 32768;
        wsb[dstoff + n * K + k] = (short)f2bf(pa.src[mi][k * 128 + n]);
        return;
    }
    idx -= 245760;
    if (idx < 320000) { atomicAdd(&hist[lld[idx]], 1); return; }
    idx -= 320000;
    if (idx < 160000) atomicAdd(&hist[10000 + kld[idx]], 1);
}

// ---------------------------------------------------------------------------
// Kernel B: blocks 0-1 = exclusive scan (hist read straight from L2, 2 passes,
// no 40KB LDS so proj blocks keep high occupancy); blocks 2.. = proj GEMMs.
// ---------------------------------------------------------------------------
struct ProjDesc { const float* A; const short* Bt; short* out; const float* bias;
                  int rows; int ktb; int co; int hasb; };
struct SPArgs {
    const int* hist; int* cursor;
    ProjDesc d[8];
};

__global__ __launch_bounds__(256) void scan_proj_kernel(SPArgs sp) {
    __shared__ __align__(16) short a_lds[64 * MSTR];   // 17408 B (proj staging)
    __shared__ int ps[256];
    const int t = threadIdx.x;
    if (blockIdx.x < 2) {
        const int b = blockIdx.x;
        const int* h = sp.hist + b * 10000;
        int* cur = sp.cursor + b * 10000;
        const int base = t * 40;
        int s = 0;
#pragma unroll 8
        for (int i = 0; i < 40; i++) { int ii = base + i; if (ii < 10000) s += h[ii]; }
        ps[t] = s;
        __syncthreads();
        for (int off = 1; off < 256; off <<= 1) {
            int v = (t >= off) ? ps[t - off] : 0;
            __syncthreads();
            ps[t] += v;
            __syncthreads();
        }
        int run = ps[t] - s;   // exclusive prefix of this chunk
        for (int i = 0; i < 40; i++) {
            int ii = base + i;
            if (ii < 10000) { cur[ii] = run; run += h[ii]; }
        }
        return;
    }
    // ---- projection part ----
    const int pb = blockIdx.x - 2;
    const int di = pb / 157, tile = pb - di * 157;
    const ProjDesc pd = sp.d[di];
    if (tile * 64 >= pd.rows) return;
    {
        const int r = t >> 2, q = t & 3;
        const int node = tile * 64 + r;
        short* arow = a_lds + r * MSTR + q * 32;
        if (node < pd.rows) {
            const float* ap = pd.A + (size_t)node * 128 + q * 32;
#pragma unroll
            for (int i = 0; i < 4; i++) {
                float4 v0 = *(const float4*)(ap + i * 8);
                float4 v1 = *(const float4*)(ap + i * 8 + 4);
                short8 o;
                o[0] = (short)f2bf(v0.x); o[1] = (short)f2bf(v0.y);
                o[2] = (short)f2bf(v0.z); o[3] = (short)f2bf(v0.w);
                o[4] = (short)f2bf(v1.x); o[5] = (short)f2bf(v1.y);
                o[6] = (short)f2bf(v1.z); o[7] = (short)f2bf(v1.w);
                *(short8*)(arow + i * 8) = o;
            }
        } else {
            short8 z = {0, 0, 0, 0, 0, 0, 0, 0};
#pragma unroll
            for (int i = 0; i < 4; i++) *(short8*)(arow + i * 8) = z;
        }
    }
    __syncthreads();

    const int ln = t & 63, wv = t >> 6;
    const int lrow = ln & 15, quad = ln >> 4;
    const int c0 = wv * 32 + lrow, c1 = c0 + 16;

    short8 bf0[4], bf1[4];
#pragma unroll
    for (int kt = 0; kt < 4; kt++) {
        bf0[kt] = *(const short8*)(pd.Bt + c0 * 256 + (pd.ktb + kt) * 32 + quad * 8);
        bf1[kt] = *(const short8*)(pd.Bt + c1 * 256 + (pd.ktb + kt) * 32 + quad * 8);
    }
    const float bb0 = pd.hasb ? pd.bias[c0] : 0.0f;
    const float bb1 = pd.hasb ? pd.bias[c1] : 0.0f;
#pragma unroll
    for (int mt = 0; mt < 4; mt++) {
        short8 af[4];
#pragma unroll
        for (int kt = 0; kt < 4; kt++)
            af[kt] = *(const short8*)(&a_lds[(mt * 16 + lrow) * MSTR + kt * 32 + quad * 8]);
        f32x4 a0 = {0.f, 0.f, 0.f, 0.f}, a1 = {0.f, 0.f, 0.f, 0.f};
#pragma unroll
        for (int kt = 0; kt < 4; kt++) {
            a0 = __builtin_amdgcn_mfma_f32_16x16x32_bf16(af[kt], bf0[kt], a0, 0, 0, 0);
            a1 = __builtin_amdgcn_mfma_f32_16x16x32_bf16(af[kt], bf1[kt], a1, 0, 0, 0);
        }
#pragma unroll
        for (int r = 0; r < 4; r++) {
            const int node = tile * 64 + mt * 16 + quad * 4 + r;
            if (node < pd.rows) {
                pd.out[(size_t)node * 256 + pd.co + c0] = (short)f2bf(a0[r] + bb0);
                pd.out[(size_t)node * 256 + pd.co + c1] = (short)f2bf(a1[r] + bb1);
            }
        }
    }
}

// ---------------------------------------------------------------------------
// Kernel C: scatter edges into dst-sorted order as int2 (src,dst)
// ---------------------------------------------------------------------------
__global__ __launch_bounds__(256) void scatter_kernel(const int* __restrict__ lls,
                                                      const int* __restrict__ lld,
                                                      const int* __restrict__ kls,
                                                      const int* __restrict__ kld,
                                                      int* __restrict__ cursor,
                                                      int2* __restrict__ ll_sdp,
                                                      int2* __restrict__ kl_sdp) {
    int i = blockIdx.x * 256 + threadIdx.x;
    if (i < 320000) {
        int d = lld[i];
        int p = atomicAdd(&cursor[d], 1);
        ll_sdp[p] = make_int2(lls[i], d);
    } else if (i < 480000) {
        int j = i - 320000;
        int d = kld[j];
        int p = atomicAdd(&cursor[10000 + d], 1);
        kl_sdp[p] = make_int2(kls[j], d);
    }
}

// ---------------------------------------------------------------------------
// Edge kernel: EPB=32, 256 threads (4 waves), wave w owns cols [32w,32w+32).
// 3 barriers: B1 (phase0->GEMMs), B2 (GEMMs done -> msg overlay safe),
// B3 (msg/gate/sv ready -> segmented scan). Waves retire early after B3.
// ---------------------------------------------------------------------------
struct EdgeSet {
    const short *Ps, *Pd;        // [nodes][256] bf16: 0..127 e-proj, 128..255 c-proj (b1 in Pd)
    const float *xs, *xd;
    const int2 *esd;             // dst-sorted (src,dst)
    const float *w256e, *w256c;  // dij coefficient rows (fp32)
    const short *W2t, *cW2t;     // [128][128] bf16 [col][k]
    const float *b2e, *b2c;
    const float *aW, *ab, *cW3;
};
struct EdgePair { EdgeSet s[2]; int split; };

__global__ __launch_bounds__(256, 8) void edge_kernel(EdgePair ep,
                                                      float* __restrict__ hne,
                                                      float* __restrict__ xne)
{
    __shared__ __align__(16) char mbuf[EPB * MSTR * 4];  // 17408: mh|mc bf16, overlay msg f32 (16896)
    __shared__ float sv_l[EPB];
    __shared__ float gate_l[EPB];
    __shared__ float xdf[3][EPB];
    __shared__ int   dstl[EPB];
    __shared__ float gpc[4][EPB];
    __shared__ float gpe[4][EPB];

    short* mh = (short*)mbuf;
    short* mc = (short*)(mbuf + EPB * MSTR * 2);
    float* msg = (float*)mbuf;          // stride 132 floats, overlays mh+mc after GEMMs

    const int isKL = (blockIdx.x >= ep.split) ? 1 : 0;
    const EdgeSet P = ep.s[isKL];
    const int eb = (blockIdx.x - (isKL ? ep.split : 0)) * EPB;
    const int t = threadIdx.x;

    // ---- phase 0: gather projections, fuse add+dij*w+silu, pack bf16 ----
    {
        const int e = t >> 3, q = t & 7;     // 8 threads/edge, 16 cols each
        const int eid = eb + e;
        const int2 sd = P.esd[eid];
        const int s = sd.x, d = sd.y;
        float dx = P.xs[s * 3 + 0] - P.xd[d * 3 + 0];
        float dy = P.xs[s * 3 + 1] - P.xd[d * 3 + 1];
        float dz = P.xs[s * 3 + 2] - P.xd[d * 3 + 2];
        float dd = sqrtf(dx * dx + dy * dy + dz * dz);
        if (q == 0) {
            dstl[e] = d;
            float inv = 1.0f / (dd + 1.0f);
            xdf[0][e] = dx * inv; xdf[1][e] = dy * inv; xdf[2][e] = dz * inv;
        }
        const short* psrow = P.Ps + (size_t)s * 256 + q * 16;
        const short* pdrow = P.Pd + (size_t)d * 256 + q * 16;
#pragma unroll
        for (int path = 0; path < 2; path++) {
            const short* ps = psrow + path * 128;
            const short* pq = pdrow + path * 128;
            const float* wq = (path ? P.w256c : P.w256e) + q * 16;
            short* mrow = (path ? mc : mh) + e * MSTR + q * 16;
#pragma unroll
            for (int i = 0; i < 2; i++) {
                short8 a = *(const short8*)(ps + i * 8);
                short8 b = *(const short8*)(pq + i * 8);
                float4 wA = *(const float4*)(wq + i * 8);
                float4 wB = *(const float4*)(wq + i * 8 + 4);
                short8 o;
                o[0] = (short)f2bf(fsilu(bf2f(a[0]) + bf2f(b[0]) + dd * wA.x));
                o[1] = (short)f2bf(fsilu(bf2f(a[1]) + bf2f(b[1]) + dd * wA.y));
                o[2] = (short)f2bf(fsilu(bf2f(a[2]) + bf2f(b[2]) + dd * wA.z));
                o[3] = (short)f2bf(fsilu(bf2f(a[3]) + bf2f(b[3]) + dd * wA.w));
                o[4] = (short)f2bf(fsilu(bf2f(a[4]) + bf2f(b[4]) + dd * wB.x));
                o[5] = (short)f2bf(fsilu(bf2f(a[5]) + bf2f(b[5]) + dd * wB.y));
                o[6] = (short)f2bf(fsilu(bf2f(a[6]) + bf2f(b[6]) + dd * wB.z));
                o[7] = (short)f2bf(fsilu(bf2f(a[7]) + bf2f(b[7]) + dd * wB.w));
                *(short8*)(mrow + i * 8) = o;
            }
        }
    }
    __syncthreads();   // B1

    const int ln = t & 63, wv = t >> 6;
    const int lrow = ln & 15, quad = ln >> 4;
    const int c0 = wv * 32 + lrow, c1 = c0 + 16;

    // ---- GEMM2c: c2 = silu(m_c @ cW2 + cb2); sv partials -> gpc ----
    {
        short8 bf0[4], bf1[4];
#pragma unroll
        for (int kt = 0; kt < 4; kt++) {
            bf0[kt] = *(const short8*)(P.cW2t + c0 * 128 + kt * 32 + quad * 8);
            bf1[kt] = *(const short8*)(P.cW2t + c1 * 128 + kt * 32 + quad * 8);
        }
        const float cw0 = P.cW3[c0], cw1 = P.cW3[c1];
        const float bb0 = P.b2c[c0], bb1 = P.b2c[c1];
#pragma unroll
        for (int mt = 0; mt < 2; mt++) {
            short8 af[4];
#pragma unroll
            for (int kt = 0; kt < 4; kt++)
                af[kt] = *(const short8*)(&mc[(mt * 16 + lrow) * MSTR + kt * 32 + quad * 8]);
            f32x4 a0 = {0.f, 0.f, 0.f, 0.f}, a1 = {0.f, 0.f, 0.f, 0.f};
#pragma unroll
            for (int kt = 0; kt < 4; kt++) {
                a0 = __builtin_amdgcn_mfma_f32_16x16x32_bf16(af[kt], bf0[kt], a0, 0, 0, 0);
                a1 = __builtin_amdgcn_mfma_f32_16x16x32_bf16(af[kt], bf1[kt], a1, 0, 0, 0);
            }
#pragma unroll
            for (int r = 0; r < 4; r++) {
                float v0 = fsilu(a0[r] + bb0);
                float v1 = fsilu(a1[r] + bb1);
                float g = v0 * cw0 + v1 * cw1;
                g += __shfl_xor(g, 1, 64);
                g += __shfl_xor(g, 2, 64);
                g += __shfl_xor(g, 4, 64);
                g += __shfl_xor(g, 8, 64);
                if (lrow == 0) gpc[wv][mt * 16 + quad * 4 + r] = g;
            }
        }
    }

    // ---- GEMM2e: m2 = silu(m_h @ eW2 + b2); gate partials -> gpe; m2 in regs ----
    float m2s[2][8];
    {
        short8 bf0[4], bf1[4];
#pragma unroll
        for (int kt = 0; kt < 4; kt++) {
            bf0[kt] = *(const short8*)(P.W2t + c0 * 128 + kt * 32 + quad * 8);
            bf1[kt] = *(const short8*)(P.W2t + c1 * 128 + kt * 32 + quad * 8);
        }
        const float aw0 = P.aW[c0], aw1 = P.aW[c1];
        const float bb0 = P.b2e[c0], bb1 = P.b2e[c1];
#pragma unroll
        for (int mt = 0; mt < 2; mt++) {
            short8 af[4];
#pragma unroll
            for (int kt = 0; kt < 4; kt++)
                af[kt] = *(const short8*)(&mh[(mt * 16 + lrow) * MSTR + kt * 32 + quad * 8]);
            f32x4 a0 = {0.f, 0.f, 0.f, 0.f}, a1 = {0.f, 0.f, 0.f, 0.f};
#pragma unroll
            for (int kt = 0; kt < 4; kt++) {
                a0 = __builtin_amdgcn_mfma_f32_16x16x32_bf16(af[kt], bf0[kt], a0, 0, 0, 0);
                a1 = __builtin_amdgcn_mfma_f32_16x16x32_bf16(af[kt], bf1[kt], a1, 0, 0, 0);
            }
#pragma unroll
            for (int r = 0; r < 4; r++) {
                float v0 = fsilu(a0[r] + bb0);
                float v1 = fsilu(a1[r] + bb1);
                m2s[mt][r] = v0; m2s[mt][4 + r] = v1;
                float g = v0 * aw0 + v1 * aw1;
                g += __shfl_xor(g, 1, 64);
                g += __shfl_xor(g, 2, 64);
                g += __shfl_xor(g, 4, 64);
                g += __shfl_xor(g, 8, 64);
                if (lrow == 0) gpe[wv][mt * 16 + quad * 4 + r] = g;
            }
        }
    }
    __syncthreads();   // B2 (all mh/mc reads done -> msg overlay safe; gpc/gpe complete)

    if (t < EPB) {
        sv_l[t]   = gpc[0][t] + gpc[1][t] + gpc[2][t] + gpc[3][t];
        gate_l[t] = fsigm(gpe[0][t] + gpe[1][t] + gpe[2][t] + gpe[3][t] + P.ab[0]);
    }
#pragma unroll
    for (int mt = 0; mt < 2; mt++)
#pragma unroll
        for (int r = 0; r < 4; r++) {
            const int erow = mt * 16 + quad * 4 + r;
            msg[erow * 132 + c0] = m2s[mt][r];
            msg[erow * 132 + c1] = m2s[mt][4 + r];
        }
    __syncthreads();   // B3 (last barrier — waves retire early below)

    // ---- segmented reductions (dst-sorted); gate folded into h-scan ----
    if (t < 128) {
        const int col = t;
        float acc = 0.0f;
        int cur = dstl[0];
#pragma unroll 4
        for (int e = 0; e < EPB; e++) {
            const int d = dstl[e];
            if (d != cur) {
                atomAddF(&hne[(size_t)cur * 128 + col], acc);
                acc = 0.0f; cur = d;
            }
            acc += msg[e * 132 + col] * gate_l[e];
        }
        atomAddF(&hne[(size_t)cur * 128 + col], acc);
    } else if (t < 131) {
        const int ax = t - 128;
        float acc = 0.0f;
        int cur = dstl[0];
        for (int e = 0; e < EPB; e++) {
            const int d = dstl[e];
            if (d != cur) {
                atomAddF(&xne[cur * 3 + ax], acc);
                acc = 0.0f; cur = d;
            }
            acc += sv_l[e] * xdf[ax][e];
        }
        atomAddF(&xne[cur * 3 + ax], acc);
    }
}

// ---------------------------------------------------------------------------
// Node kernel (unchanged)
// ---------------------------------------------------------------------------
__global__ __launch_bounds__(256) void node_kernel(
    const float* __restrict__ h_lig, const float* __restrict__ zlig,
    const short* __restrict__ W1t, const float* __restrict__ b1v,
    const short* __restrict__ W2t, const float* __restrict__ b2v,
    const float* __restrict__ x_lig,
    float* __restrict__ acc_h, float* __restrict__ acc_x)
{
    __shared__ __align__(16) short f_lds[64 * FSTR];
    __shared__ __align__(16) short m_lds[64 * MSTR];
    const int t = threadIdx.x;
    const int nb = blockIdx.x * 64;

    {
        const int e = t >> 2, q = t & 3;
        const int node = nb + e;
        short* frow = &f_lds[e * FSTR + q * 32];
        if (node < 10000) {
            const float zi = 1.0f / zlig[node];
            const float4* hp = (const float4*)(h_lig + (size_t)node * 128 + q * 32);
            const float4* np = (const float4*)(acc_h + (size_t)node * 128 + q * 32);
#pragma unroll
            for (int i = 0; i < 8; i++) {
                float4 v = hp[i];
                *(ushort4*)(frow + i * 4) =
                    make_ushort4(f2bf(v.x), f2bf(v.y), f2bf(v.z), f2bf(v.w));
            }
#pragma unroll
            for (int i = 0; i < 8; i++) {
                float4 v = np[i];
                *(ushort4*)(frow + 128 + i * 4) =
                    make_ushort4(f2bf(v.x * zi), f2bf(v.y * zi), f2bf(v.z * zi), f2bf(v.w * zi));
            }
        } else {
            const ushort4 zz = make_ushort4(0, 0, 0, 0);
#pragma unroll
            for (int i = 0; i < 8; i++) {
                *(ushort4*)(frow + i * 4) = zz;
                *(ushort4*)(frow + 128 + i * 4) = zz;
            }
        }
    }
    __syncthreads();

    const int ln = t & 63, wv = t >> 6;
    const int lrow = ln & 15, quad = ln >> 4;
    const int c0 = wv * 32 + lrow, c1 = c0 + 16;

    {
        short8 bf0[8], bf1[8];
#pragma unroll
        for (int kt = 0; kt < 8; kt++) {
            bf0[kt] = *(const short8*)(W1t + c0 * 256 + kt * 32 + quad * 8);
            bf1[kt] = *(const short8*)(W1t + c1 * 256 + kt * 32 + quad * 8);
        }
        const float bb0 = b1v[c0], bb1 = b1v[c1];
#pragma unroll
        for (int mt = 0; mt < 4; mt++) {
            short8 af[8];
#pragma unroll
            for (int kt = 0; kt < 8; kt++)
                af[kt] = *(const short8*)(&f_lds[(mt * 16 + lrow) * FSTR + kt * 32 + quad * 8]);
            f32x4 a0 = {0.f, 0.f, 0.f, 0.f}, a1 = {0.f, 0.f, 0.f, 0.f};
#pragma unroll
            for (int kt = 0; kt < 8; kt++) {
                a0 = __builtin_amdgcn_mfma_f32_16x16x32_bf16(af[kt], bf0[kt], a0, 0, 0, 0);
                a1 = __builtin_amdgcn_mfma_f32_16x16x32_bf16(af[kt], bf1[kt], a1, 0, 0, 0);
            }
#pragma unroll
            for (int r = 0; r < 4; r++) {
                const int erow = mt * 16 + quad * 4 + r;
                m_lds[erow * MSTR + c0] = (short)f2bf(fsilu(a0[r] + bb0));
                m_lds[erow * MSTR + c1] = (short)f2bf(fsilu(a1[r] + bb1));
            }
        }
    }
    __syncthreads();

    {
        short8 bf0[4], bf1[4];
#pragma unroll
        for (int kt = 0; kt < 4; kt++) {
            bf0[kt] = *(const short8*)(W2t + c0 * 128 + kt * 32 + quad * 8);
            bf1[kt] = *(const short8*)(W2t + c1 * 128 + kt * 32 + quad * 8);
        }
        const float bb0 = b2v[c0], bb1 = b2v[c1];
#pragma unroll
        for (int mt = 0; mt < 4; mt++) {
            short8 af[4];
#pragma unroll
            for (int kt = 0; kt < 4; kt++)
                af[kt] = *(const short8*)(&m_lds[(mt * 16 + lrow) * MSTR + kt * 32 + quad * 8]);
            f32x4 a0 = {0.f, 0.f, 0.f, 0.f}, a1 = {0.f, 0.f, 0.f, 0.f};
#pragma unroll
            for (int kt = 0; kt < 4; kt++) {
                a0 = __builtin_amdgcn_mfma_f32_16x16x32_bf16(af[kt], bf0[kt], a0, 0, 0, 0);
                a1 = __builtin_amdgcn_mfma_f32_16x16x32_bf16(af[kt], bf1[kt], a1, 0, 0, 0);
            }
#pragma unroll
            for (int r = 0; r < 4; r++) {
                const int node = nb + mt * 16 + quad * 4 + r;
                if (node < 10000) {
                    acc_h[(size_t)node * 128 + c0] = a0[r] + bb0 + h_lig[(size_t)node * 128 + c0];
                    acc_h[(size_t)node * 128 + c1] = a1[r] + bb1 + h_lig[(size_t)node * 128 + c1];
                }
            }
        }
    }
    if (t < 64) {
        const int node = nb + t;
        if (node < 10000) {
            const float zi = 1.0f / zlig[node];
#pragma unroll
            for (int i = 0; i < 3; i++)
                acc_x[node * 3 + i] = x_lig[node * 3 + i] + acc_x[node * 3 + i] * zi;
        }
    }
}

extern "C" void kernel_launch(void* const* d_in, const int* in_sizes, int n_in,
                              void* d_out, int out_size, void* d_ws, size_t ws_size,
                              hipStream_t stream)
{
    (void)in_sizes; (void)n_in; (void)ws_size;
    const float* h_lig  = (const float*)d_in[0];
    const float* h_kp   = (const float*)d_in[1];
    const float* x_lig  = (const float*)d_in[2];
    const float* x_kp   = (const float*)d_in[3];
    const float* z_lig  = (const float*)d_in[4];
    const float* ll_eW1 = (const float*)d_in[5];
    const float* ll_eb1 = (const float*)d_in[6];
    const float* ll_eW2 = (const float*)d_in[7];
    const float* ll_eb2 = (const float*)d_in[8];
    const float* ll_aW  = (const float*)d_in[9];
    const float* ll_ab  = (const float*)d_in[10];
    const float* ll_cW1 = (const float*)d_in[11];
    const float* ll_cb1 = (const float*)d_in[12];
    const float* ll_cW2 = (const float*)d_in[13];
    const float* ll_cb2 = (const float*)d_in[14];
    const float* ll_cW3 = (const float*)d_in[15];
    const float* kl_eW1 = (const float*)d_in[16];
    const float* kl_eb1 = (const float*)d_in[17];
    const float* kl_eW2 = (const float*)d_in[18];
    const float* kl_eb2 = (const float*)d_in[19];
    const float* kl_aW  = (const float*)d_in[20];
    const float* kl_ab  = (const float*)d_in[21];
    const float* kl_cW1 = (const float*)d_in[22];
    const float* kl_cb1 = (const float*)d_in[23];
    const float* kl_cW2 = (const float*)d_in[24];
    const float* kl_cb2 = (const float*)d_in[25];
    const float* kl_cW3 = (const float*)d_in[26];
    const float* n_W1   = (const float*)d_in[27];
    const float* n_b1   = (const float*)d_in[28];
    const float* n_W2   = (const float*)d_in[29];
    const float* n_b2   = (const float*)d_in[30];
    const int* ll_src = (const int*)d_in[31];
    const int* ll_dst = (const int*)d_in[32];
    const int* kl_src = (const int*)d_in[33];
    const int* kl_dst = (const int*)d_in[34];

    float* out = (float*)d_out;
    float* hne = out;                 // [10000,128]
    float* xne = out + 1280000;       // [10000,3]

    // ws layout (bytes) — ~20.9 MB
    char* wsc = (char*)d_ws;
    short* wsb    = (short*)wsc;                 //       0: weights (491,520 B)
    short* P_ll_s = (short*)(wsc +   491520);    // 5,120,000 B  [10000][256]
    short* P_ll_d = (short*)(wsc +  5611520);    // 5,120,000 B
    short* P_kl_s = (short*)(wsc + 10731520);    // 1,024,000 B  [2000][256]
    short* P_kl_d = (short*)(wsc + 11755520);    // 5,120,000 B
    int2* ll_sdp  = (int2*)(wsc + 16875520);     // 2,560,000 B
    int2* kl_sdp  = (int2*)(wsc + 19435520);     // 1,280,000 B
    int* hist     = (int*)(wsc + 20715520);      //    80,000 B (20000 ints)
    int* cursor   = (int*)(wsc + 20795520);      //    80,000 B -> end 20,875,520

    hipMemsetAsync(d_out, 0, (size_t)out_size * sizeof(float), stream);
    hipMemsetAsync(hist, 0, 80000, stream);

    // A. weight transpose + histogram
    {
        PrepArgs pa;
        pa.src[0] = ll_eW1; pa.src[1] = ll_eW2; pa.src[2] = ll_cW1; pa.src[3] = ll_cW2;
        pa.src[4] = kl_eW1; pa.src[5] = kl_eW2; pa.src[6] = kl_cW1; pa.src[7] = kl_cW2;
        pa.src[8] = n_W1;   pa.src[9] = n_W2;
        prep_hist_kernel<<<2835, 256, 0, stream>>>(pa, wsb, ll_dst, kl_dst, hist);
    }
    // B. scan (2 blocks) + projections (independent, overlap)
    {
        SPArgs sp;
        sp.hist = hist; sp.cursor = cursor;
        sp.d[0] = { h_lig, wsb + 0,      P_ll_s, ll_eb1, 10000, 0, 0,   0 };
        sp.d[1] = { h_lig, wsb + 49152,  P_ll_s, ll_cb1, 10000, 0, 128, 0 };
        sp.d[2] = { h_lig, wsb + 0,      P_ll_d, ll_eb1, 10000, 4, 0,   1 };
        sp.d[3] = { h_lig, wsb + 49152,  P_ll_d, ll_cb1, 10000, 4, 128, 1 };
        sp.d[4] = { h_kp,  wsb + 98304,  P_kl_s, kl_eb1,  2000, 0, 0,   0 };
        sp.d[5] = { h_kp,  wsb + 147456, P_kl_s, kl_cb1,  2000, 0, 128, 0 };
        sp.d[6] = { h_lig, wsb + 98304,  P_kl_d, kl_eb1, 10000, 4, 0,   1 };
        sp.d[7] = { h_lig, wsb + 147456, P_kl_d, kl_cb1, 10000, 4, 128, 1 };
        scan_proj_kernel<<<2 + 8 * 157, 256, 0, stream>>>(sp);
    }
    // C. scatter into sorted order (int2 pairs)
    scatter_kernel<<<1875, 256, 0, stream>>>(ll_src, ll_dst, kl_src, kl_dst, cursor,
                                             ll_sdp, kl_sdp);
    // D. edges (ll + kl in one launch), EPB=32
    {
        EdgePair ep;
        ep.split = 10000;
        ep.s[0] = { P_ll_s, P_ll_d, x_lig, x_lig, ll_sdp,
                    ll_eW1 + 256 * 128, ll_cW1 + 256 * 128,
                    wsb + 32768, wsb + 81920, ll_eb2, ll_cb2,
                    ll_aW, ll_ab, ll_cW3 };
        ep.s[1] = { P_kl_s, P_kl_d, x_kp, x_lig, kl_sdp,
                    kl_eW1 + 256 * 128, kl_cW1 + 256 * 128,
                    wsb + 131072, wsb + 180224, kl_eb2, kl_cb2,
                    kl_aW, kl_ab, kl_cW3 };
        edge_kernel<<<15000, 256, 0, stream>>>(ep, hne, xne);
    }
    // E. node MLP + final outputs
    node_kernel<<<157, 256, 0, stream>>>(
        h_lig, z_lig, wsb + 196608, n_b1, wsb + 229376, n_b2,
        x_lig, hne, xne);
}

// Round 8
// 403.203 us; speedup vs baseline: 1.3874x; 1.0600x over previous
//
#include <hip/hip_runtime.h>
#include <math.h>

#define EPB  32    // edges per block
#define MSTR 136   // m LDS row stride (shorts): 128 + 8 pad
#define FSTR 264   // node-kernel f stride

typedef __attribute__((ext_vector_type(8))) short short8;
typedef __attribute__((ext_vector_type(4))) float f32x4;

__device__ __forceinline__ unsigned short f2bf(float x) {
    unsigned int u = __float_as_uint(x);
    u += 0x7fffu + ((u >> 16) & 1u);   // round-to-nearest-even
    return (unsigned short)(u >> 16);
}
__device__ __forceinline__ float bf2f(short v) {
    return __uint_as_float(((unsigned int)(unsigned short)v) << 16);
}
// fast versions: v_rcp_f32 / v_sqrt_f32 (1 inst) instead of IEEE div/sqrt expansion
__device__ __forceinline__ float frcp(float x) { return __builtin_amdgcn_rcpf(x); }
__device__ __forceinline__ float fsilu(float x) {
    return x * frcp(1.0f + __expf(-x));
}
__device__ __forceinline__ float fsigm(float x) {
    return frcp(1.0f + __expf(-x));
}
__device__ __forceinline__ void atomAddF(float* p, float v) {
    unsafeAtomicAdd(p, v);   // hardware global_atomic_add_f32
}

// ---------------------------------------------------------------------------
// Kernel A: weight transpose (fp32 [K][128] -> bf16 [128][K]) + dst histogram
// ---------------------------------------------------------------------------
struct PrepArgs { const float* src[10]; };

__global__ __launch_bounds__(256) void prep_hist_kernel(PrepArgs pa, short* __restrict__ wsb,
                                                        const int* __restrict__ lld,
                                                        const int* __restrict__ kld,
                                                        int* __restrict__ hist) {
    int idx = blockIdx.x * 256 + threadIdx.x;
    if (idx < 245760) {
        int pair = idx / 49152;
        int rem  = idx - pair * 49152;
        int second = (rem >= 32768) ? 1 : 0;
        int mi = pair * 2 + second;
        int within = second ? (rem - 32768) : rem;
        int n, k, K;
        if (second) { K = 128; n = within >> 7; k = within & 127; }
        else        { K = 256; n = within >> 8; k = within & 255; }
        int dstoff = pair * 49152 + second * 32768;
        wsb[dstoff + n * K + k] = (short)f2bf(pa.src[mi][k * 128 + n]);
        return;
    }
    idx -= 245760;
    if (idx < 320000) { atomicAdd(&hist[lld[idx]], 1); return; }
    idx -= 320000;
    if (idx < 160000) atomicAdd(&hist[10000 + kld[idx]], 1);
}

// ---------------------------------------------------------------------------
// Kernel B: exclusive scan of 10000 bins per edge type (LDS-staged)
// ---------------------------------------------------------------------------
__global__ __launch_bounds__(256) void scan_kernel(const int* __restrict__ hist,
                                                   int* __restrict__ cursor) {
    __shared__ int bins[10000];
    __shared__ int ps[256];
    const int b = blockIdx.x, t = threadIdx.x;
    const int* h = hist + b * 10000;
    int* cur = cursor + b * 10000;
    for (int i = t; i < 10000; i += 256) bins[i] = h[i];
    __syncthreads();
    const int base = t * 40;
    int s = 0;
#pragma unroll 8
    for (int i = 0; i < 40; i++) { int ii = base + i; if (ii < 10000) s += bins[ii]; }
    ps[t] = s;
    __syncthreads();
    for (int off = 1; off < 256; off <<= 1) {
        int v = (t >= off) ? ps[t - off] : 0;
        __syncthreads();
        ps[t] += v;
        __syncthreads();
    }
    int run = ps[t] - s;   // exclusive prefix of this chunk
    for (int i = 0; i < 40; i++) {
        int ii = base + i;
        if (ii < 10000) { int c = bins[ii]; bins[ii] = run; run += c; }
    }
    __syncthreads();
    for (int i = t; i < 10000; i += 256) cur[i] = bins[i];
}

// ---------------------------------------------------------------------------
// Kernel C: fused scatter (blocks 0..1874) + projection GEMMs (blocks 1875..)
// ---------------------------------------------------------------------------
struct ProjDesc { const float* A; const short* Bt; short* out; const float* bias;
                  int rows; int ktb; int co; int hasb; };
struct CArgs {
    const int *lls, *lld, *kls, *kld;
    int* cursor;
    int *ll_ssrc, *ll_sdst, *kl_ssrc, *kl_sdst;
    ProjDesc d[8];
};

__global__ __launch_bounds__(256) void scatter_proj_kernel(CArgs ca) {
    __shared__ __align__(16) short a_lds[64 * MSTR];
    const int t = threadIdx.x;
    if (blockIdx.x < 1875) {
        int i = blockIdx.x * 256 + t;
        if (i < 320000) {
            int d = ca.lld[i];
            int p = atomicAdd(&ca.cursor[d], 1);
            ca.ll_ssrc[p] = ca.lls[i]; ca.ll_sdst[p] = d;
        } else if (i < 480000) {
            int j = i - 320000;
            int d = ca.kld[j];
            int p = atomicAdd(&ca.cursor[10000 + d], 1);
            ca.kl_ssrc[p] = ca.kls[j]; ca.kl_sdst[p] = d;
        }
        return;
    }
    const int pb = blockIdx.x - 1875;
    const int di = pb / 157, tile = pb - di * 157;
    const ProjDesc pd = ca.d[di];
    if (tile * 64 >= pd.rows) return;
    {
        const int r = t >> 2, q = t & 3;
        const int node = tile * 64 + r;
        short* arow = a_lds + r * MSTR + q * 32;
        if (node < pd.rows) {
            const float* ap = pd.A + (size_t)node * 128 + q * 32;
#pragma unroll
            for (int i = 0; i < 4; i++) {
                float4 v0 = *(const float4*)(ap + i * 8);
                float4 v1 = *(const float4*)(ap + i * 8 + 4);
                short8 o;
                o[0] = (short)f2bf(v0.x); o[1] = (short)f2bf(v0.y);
                o[2] = (short)f2bf(v0.z); o[3] = (short)f2bf(v0.w);
                o[4] = (short)f2bf(v1.x); o[5] = (short)f2bf(v1.y);
                o[6] = (short)f2bf(v1.z); o[7] = (short)f2bf(v1.w);
                *(short8*)(arow + i * 8) = o;
            }
        } else {
            short8 z = {0, 0, 0, 0, 0, 0, 0, 0};
#pragma unroll
            for (int i = 0; i < 4; i++) *(short8*)(arow + i * 8) = z;
        }
    }
    __syncthreads();

    const int ln = t & 63, wv = t >> 6;
    const int lrow = ln & 15, quad = ln >> 4;
    const int c0 = wv * 32 + lrow, c1 = c0 + 16;

    short8 bf0[4], bf1[4];
#pragma unroll
    for (int kt = 0; kt < 4; kt++) {
        bf0[kt] = *(const short8*)(pd.Bt + c0 * 256 + (pd.ktb + kt) * 32 + quad * 8);
        bf1[kt] = *(const short8*)(pd.Bt + c1 * 256 + (pd.ktb + kt) * 32 + quad * 8);
    }
    const float bb0 = pd.hasb ? pd.bias[c0] : 0.0f;
    const float bb1 = pd.hasb ? pd.bias[c1] : 0.0f;
#pragma unroll
    for (int mt = 0; mt < 4; mt++) {
        short8 af[4];
#pragma unroll
        for (int kt = 0; kt < 4; kt++)
            af[kt] = *(const short8*)(&a_lds[(mt * 16 + lrow) * MSTR + kt * 32 + quad * 8]);
        f32x4 a0 = {0.f, 0.f, 0.f, 0.f}, a1 = {0.f, 0.f, 0.f, 0.f};
#pragma unroll
        for (int kt = 0; kt < 4; kt++) {
            a0 = __builtin_amdgcn_mfma_f32_16x16x32_bf16(af[kt], bf0[kt], a0, 0, 0, 0);
            a1 = __builtin_amdgcn_mfma_f32_16x16x32_bf16(af[kt], bf1[kt], a1, 0, 0, 0);
        }
#pragma unroll
        for (int r = 0; r < 4; r++) {
            const int node = tile * 64 + mt * 16 + quad * 4 + r;
            if (node < pd.rows) {
                pd.out[(size_t)node * 256 + pd.co + c0] = (short)f2bf(a0[r] + bb0);
                pd.out[(size_t)node * 256 + pd.co + c1] = (short)f2bf(a1[r] + bb1);
            }
        }
    }
}

// ---------------------------------------------------------------------------
// Edge kernel: EPB=32, 256 threads (4 waves), 3 barriers, fast-rcp silu.
// Accumulates into WS buffers (hne/xne), NOT d_out.
// ---------------------------------------------------------------------------
struct EdgeSet {
    const short *Ps, *Pd;        // [nodes][256] bf16: 0..127 e-proj, 128..255 c-proj (b1 in Pd)
    const float *xs, *xd;
    const int *esrc, *edst;      // dst-sorted
    const float *w256e, *w256c;  // dij coefficient rows (fp32)
    const short *W2t, *cW2t;     // [128][128] bf16 [col][k]
    const float *b2e, *b2c;
    const float *aW, *ab, *cW3;
};
struct EdgePair { EdgeSet s[2]; int split; };

__global__ __launch_bounds__(256, 8) void edge_kernel(EdgePair ep,
                                                      float* __restrict__ hne,
                                                      float* __restrict__ xne)
{
    __shared__ __align__(16) char mbuf[EPB * MSTR * 4];  // 17408: mh|mc bf16, overlay msg f32
    __shared__ float sv_l[EPB];
    __shared__ float gate_l[EPB];
    __shared__ float xdf[3][EPB];
    __shared__ int   dstl[EPB];
    __shared__ float gpc[4][EPB];
    __shared__ float gpe[4][EPB];

    short* mh = (short*)mbuf;
    short* mc = (short*)(mbuf + EPB * MSTR * 2);
    float* msg = (float*)mbuf;          // stride 132 floats, overlays mh+mc after GEMMs

    const int isKL = (blockIdx.x >= ep.split) ? 1 : 0;
    const EdgeSet P = ep.s[isKL];
    const int eb = (blockIdx.x - (isKL ? ep.split : 0)) * EPB;
    const int t = threadIdx.x;

    // ---- phase 0: gather projections, fuse add+dij*w+silu, pack bf16 ----
    {
        const int e = t >> 3, q = t & 7;     // 8 threads/edge, 16 cols each
        const int eid = eb + e;
        const int s = P.esrc[eid], d = P.edst[eid];
        float dx = P.xs[s * 3 + 0] - P.xd[d * 3 + 0];
        float dy = P.xs[s * 3 + 1] - P.xd[d * 3 + 1];
        float dz = P.xs[s * 3 + 2] - P.xd[d * 3 + 2];
        float dd = __builtin_amdgcn_sqrtf(dx * dx + dy * dy + dz * dz);
        if (q == 0) {
            dstl[e] = d;
            float inv = frcp(dd + 1.0f);
            xdf[0][e] = dx * inv; xdf[1][e] = dy * inv; xdf[2][e] = dz * inv;
        }
        const short* psrow = P.Ps + (size_t)s * 256 + q * 16;
        const short* pdrow = P.Pd + (size_t)d * 256 + q * 16;
#pragma unroll
        for (int path = 0; path < 2; path++) {
            const short* ps = psrow + path * 128;
            const short* pq = pdrow + path * 128;
            const float* wq = (path ? P.w256c : P.w256e) + q * 16;
            short* mrow = (path ? mc : mh) + e * MSTR + q * 16;
#pragma unroll
            for (int i = 0; i < 2; i++) {
                short8 a = *(const short8*)(ps + i * 8);
                short8 b = *(const short8*)(pq + i * 8);
                float4 wA = *(const float4*)(wq + i * 8);
                float4 wB = *(const float4*)(wq + i * 8 + 4);
                short8 o;
                o[0] = (short)f2bf(fsilu(bf2f(a[0]) + bf2f(b[0]) + dd * wA.x));
                o[1] = (short)f2bf(fsilu(bf2f(a[1]) + bf2f(b[1]) + dd * wA.y));
                o[2] = (short)f2bf(fsilu(bf2f(a[2]) + bf2f(b[2]) + dd * wA.z));
                o[3] = (short)f2bf(fsilu(bf2f(a[3]) + bf2f(b[3]) + dd * wA.w));
                o[4] = (short)f2bf(fsilu(bf2f(a[4]) + bf2f(b[4]) + dd * wB.x));
                o[5] = (short)f2bf(fsilu(bf2f(a[5]) + bf2f(b[5]) + dd * wB.y));
                o[6] = (short)f2bf(fsilu(bf2f(a[6]) + bf2f(b[6]) + dd * wB.z));
                o[7] = (short)f2bf(fsilu(bf2f(a[7]) + bf2f(b[7]) + dd * wB.w));
                *(short8*)(mrow + i * 8) = o;
            }
        }
    }
    __syncthreads();   // B1

    const int ln = t & 63, wv = t >> 6;
    const int lrow = ln & 15, quad = ln >> 4;
    const int c0 = wv * 32 + lrow, c1 = c0 + 16;

    // ---- GEMM2c: c2 = silu(m_c @ cW2 + cb2); sv partials -> gpc ----
    {
        short8 bf0[4], bf1[4];
#pragma unroll
        for (int kt = 0; kt < 4; kt++) {
            bf0[kt] = *(const short8*)(P.cW2t + c0 * 128 + kt * 32 + quad * 8);
            bf1[kt] = *(const short8*)(P.cW2t + c1 * 128 + kt * 32 + quad * 8);
        }
        const float cw0 = P.cW3[c0], cw1 = P.cW3[c1];
        const float bb0 = P.b2c[c0], bb1 = P.b2c[c1];
#pragma unroll
        for (int mt = 0; mt < 2; mt++) {
            short8 af[4];
#pragma unroll
            for (int kt = 0; kt < 4; kt++)
                af[kt] = *(const short8*)(&mc[(mt * 16 + lrow) * MSTR + kt * 32 + quad * 8]);
            f32x4 a0 = {0.f, 0.f, 0.f, 0.f}, a1 = {0.f, 0.f, 0.f, 0.f};
#pragma unroll
            for (int kt = 0; kt < 4; kt++) {
                a0 = __builtin_amdgcn_mfma_f32_16x16x32_bf16(af[kt], bf0[kt], a0, 0, 0, 0);
                a1 = __builtin_amdgcn_mfma_f32_16x16x32_bf16(af[kt], bf1[kt], a1, 0, 0, 0);
            }
#pragma unroll
            for (int r = 0; r < 4; r++) {
                float v0 = fsilu(a0[r] + bb0);
                float v1 = fsilu(a1[r] + bb1);
                float g = v0 * cw0 + v1 * cw1;
                g += __shfl_xor(g, 1, 64);
                g += __shfl_xor(g, 2, 64);
                g += __shfl_xor(g, 4, 64);
                g += __shfl_xor(g, 8, 64);
                if (lrow == 0) gpc[wv][mt * 16 + quad * 4 + r] = g;
            }
        }
    }

    // ---- GEMM2e: m2 = silu(m_h @ eW2 + b2); gate partials -> gpe; m2 in regs ----
    float m2s[2][8];
    {
        short8 bf0[4], bf1[4];
#pragma unroll
        for (int kt = 0; kt < 4; kt++) {
            bf0[kt] = *(const short8*)(P.W2t + c0 * 128 + kt * 32 + quad * 8);
            bf1[kt] = *(const short8*)(P.W2t + c1 * 128 + kt * 32 + quad * 8);
        }
        const float aw0 = P.aW[c0], aw1 = P.aW[c1];
        const float bb0 = P.b2e[c0], bb1 = P.b2e[c1];
#pragma unroll
        for (int mt = 0; mt < 2; mt++) {
            short8 af[4];
#pragma unroll
            for (int kt = 0; kt < 4; kt++)
                af[kt] = *(const short8*)(&mh[(mt * 16 + lrow) * MSTR + kt * 32 + quad * 8]);
            f32x4 a0 = {0.f, 0.f, 0.f, 0.f}, a1 = {0.f, 0.f, 0.f, 0.f};
#pragma unroll
            for (int kt = 0; kt < 4; kt++) {
                a0 = __builtin_amdgcn_mfma_f32_16x16x32_bf16(af[kt], bf0[kt], a0, 0, 0, 0);
                a1 = __builtin_amdgcn_mfma_f32_16x16x32_bf16(af[kt], bf1[kt], a1, 0, 0, 0);
            }
#pragma unroll
            for (int r = 0; r < 4; r++) {
                float v0 = fsilu(a0[r] + bb0);
                float v1 = fsilu(a1[r] + bb1);
                m2s[mt][r] = v0; m2s[mt][4 + r] = v1;
                float g = v0 * aw0 + v1 * aw1;
                g += __shfl_xor(g, 1, 64);
                g += __shfl_xor(g, 2, 64);
                g += __shfl_xor(g, 4, 64);
                g += __shfl_xor(g, 8, 64);
                if (lrow == 0) gpe[wv][mt * 16 + quad * 4 + r] = g;
            }
        }
    }
    __syncthreads();   // B2 (mh/mc reads done -> msg overlay safe; gpc/gpe complete)

    if (t < EPB) {
        sv_l[t]   = gpc[0][t] + gpc[1][t] + gpc[2][t] + gpc[3][t];
        gate_l[t] = fsigm(gpe[0][t] + gpe[1][t] + gpe[2][t] + gpe[3][t] + P.ab[0]);
    }
#pragma unroll
    for (int mt = 0; mt < 2; mt++)
#pragma unroll
        for (int r = 0; r < 4; r++) {
            const int erow = mt * 16 + quad * 4 + r;
            msg[erow * 132 + c0] = m2s[mt][r];
            msg[erow * 132 + c1] = m2s[mt][4 + r];
        }
    __syncthreads();   // B3 (last barrier)

    // ---- segmented reductions (dst-sorted); gate folded into h-scan ----
    if (t < 128) {
        const int col = t;
        float acc = 0.0f;
        int cur = dstl[0];
#pragma unroll 4
        for (int e = 0; e < EPB; e++) {
            const int d = dstl[e];
            if (d != cur) {
                atomAddF(&hne[(size_t)cur * 128 + col], acc);
                acc = 0.0f; cur = d;
            }
            acc += msg[e * 132 + col] * gate_l[e];
        }
        atomAddF(&hne[(size_t)cur * 128 + col], acc);
    } else if (t < 131) {
        const int ax = t - 128;
        float acc = 0.0f;
        int cur = dstl[0];
        for (int e = 0; e < EPB; e++) {
            const int d = dstl[e];
            if (d != cur) {
                atomAddF(&xne[cur * 3 + ax], acc);
                acc = 0.0f; cur = d;
            }
            acc += sv_l[e] * xdf[ax][e];
        }
        atomAddF(&xne[cur * 3 + ax], acc);
    }
}

// ---------------------------------------------------------------------------
// Node kernel: reads WS accumulators, writes d_out exactly once per element.
// ---------------------------------------------------------------------------
__global__ __launch_bounds__(256) void node_kernel(
    const float* __restrict__ h_lig, const float* __restrict__ zlig,
    const short* __restrict__ W1t, const float* __restrict__ b1v,
    const short* __restrict__ W2t, const float* __restrict__ b2v,
    const float* __restrict__ x_lig,
    const float* __restrict__ acc_h, const float* __restrict__ acc_x,
    float* __restrict__ h_out, float* __restrict__ x_out)
{
    __shared__ __align__(16) short f_lds[64 * FSTR];
    __shared__ __align__(16) short m_lds[64 * MSTR];
    const int t = threadIdx.x;
    const int nb = blockIdx.x * 64;

    {
        const int e = t >> 2, q = t & 3;
        const int node = nb + e;
        short* frow = &f_lds[e * FSTR + q * 32];
        if (node < 10000) {
            const float zi = frcp(zlig[node]);
            const float4* hp = (const float4*)(h_lig + (size_t)node * 128 + q * 32);
            const float4* np = (const float4*)(acc_h + (size_t)node * 128 + q * 32);
#pragma unroll
            for (int i = 0; i < 8; i++) {
                float4 v = hp[i];
                *(ushort4*)(frow + i * 4) =
                    make_ushort4(f2bf(v.x), f2bf(v.y), f2bf(v.z), f2bf(v.w));
            }
#pragma unroll
            for (int i = 0; i < 8; i++) {
                float4 v = np[i];
                *(ushort4*)(frow + 128 + i * 4) =
                    make_ushort4(f2bf(v.x * zi), f2bf(v.y * zi), f2bf(v.z * zi), f2bf(v.w * zi));
            }
        } else {
            const ushort4 zz = make_ushort4(0, 0, 0, 0);
#pragma unroll
            for (int i = 0; i < 8; i++) {
                *(ushort4*)(frow + i * 4) = zz;
                *(ushort4*)(frow + 128 + i * 4) = zz;
            }
        }
    }
    __syncthreads();

    const int ln = t & 63, wv = t >> 6;
    const int lrow = ln & 15, quad = ln >> 4;
    const int c0 = wv * 32 + lrow, c1 = c0 + 16;

    {
        short8 bf0[8], bf1[8];
#pragma unroll
        for (int kt = 0; kt < 8; kt++) {
            bf0[kt] = *(const short8*)(W1t + c0 * 256 + kt * 32 + quad * 8);
            bf1[kt] = *(const short8*)(W1t + c1 * 256 + kt * 32 + quad * 8);
        }
        const float bb0 = b1v[c0], bb1 = b1v[c1];
#pragma unroll
        for (int mt = 0; mt < 4; mt++) {
            short8 af[8];
#pragma unroll
            for (int kt = 0; kt < 8; kt++)
                af[kt] = *(const short8*)(&f_lds[(mt * 16 + lrow) * FSTR + kt * 32 + quad * 8]);
            f32x4 a0 = {0.f, 0.f, 0.f, 0.f}, a1 = {0.f, 0.f, 0.f, 0.f};
#pragma unroll
            for (int kt = 0; kt < 8; kt++) {
                a0 = __builtin_amdgcn_mfma_f32_16x16x32_bf16(af[kt], bf0[kt], a0, 0, 0, 0);
                a1 = __builtin_amdgcn_mfma_f32_16x16x32_bf16(af[kt], bf1[kt], a1, 0, 0, 0);
            }
#pragma unroll
            for (int r = 0; r < 4; r++) {
                const int erow = mt * 16 + quad * 4 + r;
                m_lds[erow * MSTR + c0] = (short)f2bf(fsilu(a0[r] + bb0));
                m_lds[erow * MSTR + c1] = (short)f2bf(fsilu(a1[r] + bb1));
            }
        }
    }
    __syncthreads();

    {
        short8 bf0[4], bf1[4];
#pragma unroll
        for (int kt = 0; kt < 4; kt++) {
            bf0[kt] = *(const short8*)(W2t + c0 * 128 + kt * 32 + quad * 8);
            bf1[kt] = *(const short8*)(W2t + c1 * 128 + kt * 32 + quad * 8);
        }
        const float bb0 = b2v[c0], bb1 = b2v[c1];
#pragma unroll
        for (int mt = 0; mt < 4; mt++) {
            short8 af[4];
#pragma unroll
            for (int kt = 0; kt < 4; kt++)
                af[kt] = *(const short8*)(&m_lds[(mt * 16 + lrow) * MSTR + kt * 32 + quad * 8]);
            f32x4 a0 = {0.f, 0.f, 0.f, 0.f}, a1 = {0.f, 0.f, 0.f, 0.f};
#pragma unroll
            for (int kt = 0; kt < 4; kt++) {
                a0 = __builtin_amdgcn_mfma_f32_16x16x32_bf16(af[kt], bf0[kt], a0, 0, 0, 0);
                a1 = __builtin_amdgcn_mfma_f32_16x16x32_bf16(af[kt], bf1[kt], a1, 0, 0, 0);
            }
#pragma unroll
            for (int r = 0; r < 4; r++) {
                const int node = nb + mt * 16 + quad * 4 + r;
                if (node < 10000) {
                    h_out[(size_t)node * 128 + c0] = a0[r] + bb0 + h_lig[(size_t)node * 128 + c0];
                    h_out[(size_t)node * 128 + c1] = a1[r] + bb1 + h_lig[(size_t)node * 128 + c1];
                }
            }
        }
    }
    if (t < 64) {
        const int node = nb + t;
        if (node < 10000) {
            const float zi = frcp(zlig[node]);
#pragma unroll
            for (int i = 0; i < 3; i++)
                x_out[node * 3 + i] = x_lig[node * 3 + i] + acc_x[node * 3 + i] * zi;
        }
    }
}

extern "C" void kernel_launch(void* const* d_in, const int* in_sizes, int n_in,
                              void* d_out, int out_size, void* d_ws, size_t ws_size,
                              hipStream_t stream)
{
    (void)in_sizes; (void)n_in; (void)ws_size; (void)out_size;
    const float* h_lig  = (const float*)d_in[0];
    const float* h_kp   = (const float*)d_in[1];
    const float* x_lig  = (const float*)d_in[2];
    const float* x_kp   = (const float*)d_in[3];
    const float* z_lig  = (const float*)d_in[4];
    const float* ll_eW1 = (const float*)d_in[5];
    const float* ll_eb1 = (const float*)d_in[6];
    const float* ll_eW2 = (const float*)d_in[7];
    const float* ll_eb2 = (const float*)d_in[8];
    const float* ll_aW  = (const float*)d_in[9];
    const float* ll_ab  = (const float*)d_in[10];
    const float* ll_cW1 = (const float*)d_in[11];
    const float* ll_cb1 = (const float*)d_in[12];
    const float* ll_cW2 = (const float*)d_in[13];
    const float* ll_cb2 = (const float*)d_in[14];
    const float* ll_cW3 = (const float*)d_in[15];
    const float* kl_eW1 = (const float*)d_in[16];
    const float* kl_eb1 = (const float*)d_in[17];
    const float* kl_eW2 = (const float*)d_in[18];
    const float* kl_eb2 = (const float*)d_in[19];
    const float* kl_aW  = (const float*)d_in[20];
    const float* kl_ab  = (const float*)d_in[21];
    const float* kl_cW1 = (const float*)d_in[22];
    const float* kl_cb1 = (const float*)d_in[23];
    const float* kl_cW2 = (const float*)d_in[24];
    const float* kl_cb2 = (const float*)d_in[25];
    const float* kl_cW3 = (const float*)d_in[26];
    const float* n_W1   = (const float*)d_in[27];
    const float* n_b1   = (const float*)d_in[28];
    const float* n_W2   = (const float*)d_in[29];
    const float* n_b2   = (const float*)d_in[30];
    const int* ll_src = (const int*)d_in[31];
    const int* ll_dst = (const int*)d_in[32];
    const int* kl_src = (const int*)d_in[33];
    const int* kl_dst = (const int*)d_in[34];

    float* h_out = (float*)d_out;            // [10000,128]
    float* x_out = h_out + 1280000;          // [10000,3]

    // ws layout (bytes) — ~26.1 MB; accumulators now live in WS (d_out write-once)
    char* wsc = (char*)d_ws;
    short* wsb    = (short*)wsc;                 //       0: weights (491,520 B)
    short* P_ll_s = (short*)(wsc +   491520);    // 5,120,000 B  [10000][256]
    short* P_ll_d = (short*)(wsc +  5611520);    // 5,120,000 B
    short* P_kl_s = (short*)(wsc + 10731520);    // 1,024,000 B  [2000][256]
    short* P_kl_d = (short*)(wsc + 11755520);    // 5,120,000 B
    int* ll_ssrc  = (int*)(wsc + 16875520);      // 1,280,000 B
    int* ll_sdst  = (int*)(wsc + 18155520);      // 1,280,000 B
    int* kl_ssrc  = (int*)(wsc + 19435520);      //   640,000 B
    int* kl_sdst  = (int*)(wsc + 20075520);      //   640,000 B
    int* hist     = (int*)(wsc + 20715520);      //    80,000 B (20000 ints)
    int* cursor   = (int*)(wsc + 20795520);      //    80,000 B
    float* hne    = (float*)(wsc + 20875520);    // 5,120,000 B  [10000][128]
    float* xne    = (float*)(wsc + 25995520);    //   120,000 B  [10000][3] -> end 26,115,520

    hipMemsetAsync(hne, 0, 5240000, stream);     // hne + xne (contiguous)
    hipMemsetAsync(hist, 0, 80000, stream);

    // A. weight transpose + histogram
    {
        PrepArgs pa;
        pa.src[0] = ll_eW1; pa.src[1] = ll_eW2; pa.src[2] = ll_cW1; pa.src[3] = ll_cW2;
        pa.src[4] = kl_eW1; pa.src[5] = kl_eW2; pa.src[6] = kl_cW1; pa.src[7] = kl_cW2;
        pa.src[8] = n_W1;   pa.src[9] = n_W2;
        prep_hist_kernel<<<2835, 256, 0, stream>>>(pa, wsb, ll_dst, kl_dst, hist);
    }
    // B. scan
    scan_kernel<<<2, 256, 0, stream>>>(hist, cursor);
    // C. scatter + projections fused
    {
        CArgs ca;
        ca.lls = ll_src; ca.lld = ll_dst; ca.kls = kl_src; ca.kld = kl_dst;
        ca.cursor = cursor;
        ca.ll_ssrc = ll_ssrc; ca.ll_sdst = ll_sdst;
        ca.kl_ssrc = kl_ssrc; ca.kl_sdst = kl_sdst;
        ca.d[0] = { h_lig, wsb + 0,      P_ll_s, ll_eb1, 10000, 0, 0,   0 };
        ca.d[1] = { h_lig, wsb + 49152,  P_ll_s, ll_cb1, 10000, 0, 128, 0 };
        ca.d[2] = { h_lig, wsb + 0,      P_ll_d, ll_eb1, 10000, 4, 0,   1 };
        ca.d[3] = { h_lig, wsb + 49152,  P_ll_d, ll_cb1, 10000, 4, 128, 1 };
        ca.d[4] = { h_kp,  wsb + 98304,  P_kl_s, kl_eb1,  2000, 0, 0,   0 };
        ca.d[5] = { h_kp,  wsb + 147456, P_kl_s, kl_cb1,  2000, 0, 128, 0 };
        ca.d[6] = { h_lig, wsb + 98304,  P_kl_d, kl_eb1, 10000, 4, 0,   1 };
        ca.d[7] = { h_lig, wsb + 147456, P_kl_d, kl_cb1, 10000, 4, 128, 1 };
        scatter_proj_kernel<<<1875 + 8 * 157, 256, 0, stream>>>(ca);
    }
    // D. edges (ll + kl in one launch), EPB=32
    {
        EdgePair ep;
        ep.split = 10000;
        ep.s[0] = { P_ll_s, P_ll_d, x_lig, x_lig, ll_ssrc, ll_sdst,
                    ll_eW1 + 256 * 128, ll_cW1 + 256 * 128,
                    wsb + 32768, wsb + 81920, ll_eb2, ll_cb2,
                    ll_aW, ll_ab, ll_cW3 };
        ep.s[1] = { P_kl_s, P_kl_d, x_kp, x_lig, kl_ssrc, kl_sdst,
                    kl_eW1 + 256 * 128, kl_cW1 + 256 * 128,
                    wsb + 131072, wsb + 180224, kl_eb2, kl_cb2,
                    kl_aW, kl_ab, kl_cW3 };
        edge_kernel<<<15000, 256, 0, stream>>>(ep, hne, xne);
    }
    // E. node MLP -> final outputs into d_out (write-once)
    node_kernel<<<157, 256, 0, stream>>>(
        h_lig, z_lig, wsb + 196608, n_b1, wsb + 229376, n_b2,
        x_lig, hne, xne, h_out, x_out);
}

// Round 9
// 401.011 us; speedup vs baseline: 1.3950x; 1.0055x over previous
//
#include <hip/hip_runtime.h>
#include <hip/hip_bf16.h>
#include <math.h>

#define EPB  32    // edges per block
#define MSTR 136   // m LDS row stride (shorts): 128 + 8 pad
#define FSTR 264   // node-kernel f stride

typedef __attribute__((ext_vector_type(8))) short short8;
typedef __attribute__((ext_vector_type(4))) float f32x4;

__device__ __forceinline__ unsigned short f2bf(float x) {
    unsigned int u = __float_as_uint(x);
    u += 0x7fffu + ((u >> 16) & 1u);   // round-to-nearest-even
    return (unsigned short)(u >> 16);
}
__device__ __forceinline__ float bf2f(short v) {
    return __uint_as_float(((unsigned int)(unsigned short)v) << 16);
}
// packed f32x2 -> bf16x2 (v_cvt_pk_bf16_f32 where available): 1 inst vs 6
__device__ __forceinline__ unsigned int pkbf(float a, float b) {
    __hip_bfloat162 h = __float22bfloat162_rn(make_float2(a, b));
    union { __hip_bfloat162 h2; unsigned int u; } cv; cv.h2 = h; return cv.u;
}
// fast versions: v_rcp_f32 / v_sqrt_f32 (1 inst) instead of IEEE div/sqrt expansion
__device__ __forceinline__ float frcp(float x) { return __builtin_amdgcn_rcpf(x); }
__device__ __forceinline__ float fsilu(float x) {
    return x * frcp(1.0f + __expf(-x));
}
__device__ __forceinline__ float fsigm(float x) {
    return frcp(1.0f + __expf(-x));
}
__device__ __forceinline__ void atomAddF(float* p, float v) {
    unsafeAtomicAdd(p, v);   // hardware global_atomic_add_f32
}

// ---------------------------------------------------------------------------
// Kernel A: weight transpose (fp32 [K][128] -> bf16 [128][K]) + dst histogram
// ---------------------------------------------------------------------------
struct PrepArgs { const float* src[10]; };

__global__ __launch_bounds__(256) void prep_hist_kernel(PrepArgs pa, short* __restrict__ wsb,
                                                        const int* __restrict__ lld,
                                                        const int* __restrict__ kld,
                                                        int* __restrict__ hist) {
    int idx = blockIdx.x * 256 + threadIdx.x;
    if (idx < 245760) {
        int pair = idx / 49152;
        int rem  = idx - pair * 49152;
        int second = (rem >= 32768) ? 1 : 0;
        int mi = pair * 2 + second;
        int within = second ? (rem - 32768) : rem;
        int n, k, K;
        if (second) { K = 128; n = within >> 7; k = within & 127; }
        else        { K = 256; n = within >> 8; k = within & 255; }
        int dstoff = pair * 49152 + second * 32768;
        wsb[dstoff + n * K + k] = (short)f2bf(pa.src[mi][k * 128 + n]);
        return;
    }
    idx -= 245760;
    if (idx < 320000) { atomicAdd(&hist[lld[idx]], 1); return; }
    idx -= 320000;
    if (idx < 160000) atomicAdd(&hist[10000 + kld[idx]], 1);
}

// ---------------------------------------------------------------------------
// Kernel B: exclusive scan of 10000 bins per edge type (LDS-staged)
// ---------------------------------------------------------------------------
__global__ __launch_bounds__(256) void scan_kernel(const int* __restrict__ hist,
                                                   int* __restrict__ cursor) {
    __shared__ int bins[10000];
    __shared__ int ps[256];
    const int b = blockIdx.x, t = threadIdx.x;
    const int* h = hist + b * 10000;
    int* cur = cursor + b * 10000;
    for (int i = t; i < 10000; i += 256) bins[i] = h[i];
    __syncthreads();
    const int base = t * 40;
    int s = 0;
#pragma unroll 8
    for (int i = 0; i < 40; i++) { int ii = base + i; if (ii < 10000) s += bins[ii]; }
    ps[t] = s;
    __syncthreads();
    for (int off = 1; off < 256; off <<= 1) {
        int v = (t >= off) ? ps[t - off] : 0;
        __syncthreads();
        ps[t] += v;
        __syncthreads();
    }
    int run = ps[t] - s;   // exclusive prefix of this chunk
    for (int i = 0; i < 40; i++) {
        int ii = base + i;
        if (ii < 10000) { int c = bins[ii]; bins[ii] = run; run += c; }
    }
    __syncthreads();
    for (int i = t; i < 10000; i += 256) cur[i] = bins[i];
}

// ---------------------------------------------------------------------------
// Kernel C: fused scatter (blocks 0..1874) + projection GEMMs (blocks 1875..)
// ---------------------------------------------------------------------------
struct ProjDesc { const float* A; const short* Bt; short* out; const float* bias;
                  int rows; int ktb; int co; int hasb; };
struct CArgs {
    const int *lls, *lld, *kls, *kld;
    int* cursor;
    int *ll_ssrc, *ll_sdst, *kl_ssrc, *kl_sdst;
    ProjDesc d[8];
};

__global__ __launch_bounds__(256) void scatter_proj_kernel(CArgs ca) {
    __shared__ __align__(16) short a_lds[64 * MSTR];
    const int t = threadIdx.x;
    if (blockIdx.x < 1875) {
        int i = blockIdx.x * 256 + t;
        if (i < 320000) {
            int d = ca.lld[i];
            int p = atomicAdd(&ca.cursor[d], 1);
            ca.ll_ssrc[p] = ca.lls[i]; ca.ll_sdst[p] = d;
        } else if (i < 480000) {
            int j = i - 320000;
            int d = ca.kld[j];
            int p = atomicAdd(&ca.cursor[10000 + d], 1);
            ca.kl_ssrc[p] = ca.kls[j]; ca.kl_sdst[p] = d;
        }
        return;
    }
    const int pb = blockIdx.x - 1875;
    const int di = pb / 157, tile = pb - di * 157;
    const ProjDesc pd = ca.d[di];
    if (tile * 64 >= pd.rows) return;
    {
        const int r = t >> 2, q = t & 3;
        const int node = tile * 64 + r;
        short* arow = a_lds + r * MSTR + q * 32;
        if (node < pd.rows) {
            const float* ap = pd.A + (size_t)node * 128 + q * 32;
#pragma unroll
            for (int i = 0; i < 4; i++) {
                float4 v0 = *(const float4*)(ap + i * 8);
                float4 v1 = *(const float4*)(ap + i * 8 + 4);
                uint4 o;
                o.x = pkbf(v0.x, v0.y); o.y = pkbf(v0.z, v0.w);
                o.z = pkbf(v1.x, v1.y); o.w = pkbf(v1.z, v1.w);
                *(uint4*)(arow + i * 8) = o;
            }
        } else {
            uint4 z = make_uint4(0, 0, 0, 0);
#pragma unroll
            for (int i = 0; i < 4; i++) *(uint4*)(arow + i * 8) = z;
        }
    }
    __syncthreads();

    const int ln = t & 63, wv = t >> 6;
    const int lrow = ln & 15, quad = ln >> 4;
    const int c0 = wv * 32 + lrow, c1 = c0 + 16;

    short8 bf0[4], bf1[4];
#pragma unroll
    for (int kt = 0; kt < 4; kt++) {
        bf0[kt] = *(const short8*)(pd.Bt + c0 * 256 + (pd.ktb + kt) * 32 + quad * 8);
        bf1[kt] = *(const short8*)(pd.Bt + c1 * 256 + (pd.ktb + kt) * 32 + quad * 8);
    }
    const float bb0 = pd.hasb ? pd.bias[c0] : 0.0f;
    const float bb1 = pd.hasb ? pd.bias[c1] : 0.0f;
#pragma unroll
    for (int mt = 0; mt < 4; mt++) {
        short8 af[4];
#pragma unroll
        for (int kt = 0; kt < 4; kt++)
            af[kt] = *(const short8*)(&a_lds[(mt * 16 + lrow) * MSTR + kt * 32 + quad * 8]);
        f32x4 a0 = {0.f, 0.f, 0.f, 0.f}, a1 = {0.f, 0.f, 0.f, 0.f};
#pragma unroll
        for (int kt = 0; kt < 4; kt++) {
            a0 = __builtin_amdgcn_mfma_f32_16x16x32_bf16(af[kt], bf0[kt], a0, 0, 0, 0);
            a1 = __builtin_amdgcn_mfma_f32_16x16x32_bf16(af[kt], bf1[kt], a1, 0, 0, 0);
        }
#pragma unroll
        for (int r = 0; r < 4; r++) {
            const int node = tile * 64 + mt * 16 + quad * 4 + r;
            if (node < pd.rows) {
                pd.out[(size_t)node * 256 + pd.co + c0] = (short)f2bf(a0[r] + bb0);
                pd.out[(size_t)node * 256 + pd.co + c1] = (short)f2bf(a1[r] + bb1);
            }
        }
    }
}

// ---------------------------------------------------------------------------
// Edge kernel: EPB=32, 256 threads (4 waves), 3 barriers, fast-rcp silu,
// packed bf16 converts in phase-0. Accumulates into WS buffers.
// ---------------------------------------------------------------------------
struct EdgeSet {
    const short *Ps, *Pd;        // [nodes][256] bf16: 0..127 e-proj, 128..255 c-proj (b1 in Pd)
    const float *xs, *xd;
    const int *esrc, *edst;      // dst-sorted
    const float *w256e, *w256c;  // dij coefficient rows (fp32)
    const short *W2t, *cW2t;     // [128][128] bf16 [col][k]
    const float *b2e, *b2c;
    const float *aW, *ab, *cW3;
};
struct EdgePair { EdgeSet s[2]; int split; };

__global__ __launch_bounds__(256, 8) void edge_kernel(EdgePair ep,
                                                      float* __restrict__ hne,
                                                      float* __restrict__ xne)
{
    __shared__ __align__(16) char mbuf[EPB * MSTR * 4];  // 17408: mh|mc bf16, overlay msg f32
    __shared__ float sv_l[EPB];
    __shared__ float gate_l[EPB];
    __shared__ float xdf[3][EPB];
    __shared__ int   dstl[EPB];
    __shared__ float gpc[4][EPB];
    __shared__ float gpe[4][EPB];

    short* mh = (short*)mbuf;
    short* mc = (short*)(mbuf + EPB * MSTR * 2);
    float* msg = (float*)mbuf;          // stride 132 floats, overlays mh+mc after GEMMs

    const int isKL = (blockIdx.x >= ep.split) ? 1 : 0;
    const EdgeSet P = ep.s[isKL];
    const int eb = (blockIdx.x - (isKL ? ep.split : 0)) * EPB;
    const int t = threadIdx.x;

    // ---- phase 0: gather projections, fuse add+dij*w+silu, pack bf16 ----
    {
        const int e = t >> 3, q = t & 7;     // 8 threads/edge, 16 cols each
        const int eid = eb + e;
        const int s = P.esrc[eid], d = P.edst[eid];
        float dx = P.xs[s * 3 + 0] - P.xd[d * 3 + 0];
        float dy = P.xs[s * 3 + 1] - P.xd[d * 3 + 1];
        float dz = P.xs[s * 3 + 2] - P.xd[d * 3 + 2];
        float dd = __builtin_amdgcn_sqrtf(dx * dx + dy * dy + dz * dz);
        if (q == 0) {
            dstl[e] = d;
            float inv = frcp(dd + 1.0f);
            xdf[0][e] = dx * inv; xdf[1][e] = dy * inv; xdf[2][e] = dz * inv;
        }
        const short* psrow = P.Ps + (size_t)s * 256 + q * 16;
        const short* pdrow = P.Pd + (size_t)d * 256 + q * 16;
#pragma unroll
        for (int path = 0; path < 2; path++) {
            const short* ps = psrow + path * 128;
            const short* pq = pdrow + path * 128;
            const float* wq = (path ? P.w256c : P.w256e) + q * 16;
            short* mrow = (path ? mc : mh) + e * MSTR + q * 16;
#pragma unroll
            for (int i = 0; i < 2; i++) {
                short8 a = *(const short8*)(ps + i * 8);
                short8 b = *(const short8*)(pq + i * 8);
                float4 wA = *(const float4*)(wq + i * 8);
                float4 wB = *(const float4*)(wq + i * 8 + 4);
                float v0 = fsilu(bf2f(a[0]) + bf2f(b[0]) + dd * wA.x);
                float v1 = fsilu(bf2f(a[1]) + bf2f(b[1]) + dd * wA.y);
                float v2 = fsilu(bf2f(a[2]) + bf2f(b[2]) + dd * wA.z);
                float v3 = fsilu(bf2f(a[3]) + bf2f(b[3]) + dd * wA.w);
                float v4 = fsilu(bf2f(a[4]) + bf2f(b[4]) + dd * wB.x);
                float v5 = fsilu(bf2f(a[5]) + bf2f(b[5]) + dd * wB.y);
                float v6 = fsilu(bf2f(a[6]) + bf2f(b[6]) + dd * wB.z);
                float v7 = fsilu(bf2f(a[7]) + bf2f(b[7]) + dd * wB.w);
                uint4 o;
                o.x = pkbf(v0, v1); o.y = pkbf(v2, v3);
                o.z = pkbf(v4, v5); o.w = pkbf(v6, v7);
                *(uint4*)(mrow + i * 8) = o;
            }
        }
    }
    __syncthreads();   // B1

    const int ln = t & 63, wv = t >> 6;
    const int lrow = ln & 15, quad = ln >> 4;
    const int c0 = wv * 32 + lrow, c1 = c0 + 16;

    // ---- GEMM2c: c2 = silu(m_c @ cW2 + cb2); sv partials -> gpc ----
    {
        short8 bf0[4], bf1[4];
#pragma unroll
        for (int kt = 0; kt < 4; kt++) {
            bf0[kt] = *(const short8*)(P.cW2t + c0 * 128 + kt * 32 + quad * 8);
            bf1[kt] = *(const short8*)(P.cW2t + c1 * 128 + kt * 32 + quad * 8);
        }
        const float cw0 = P.cW3[c0], cw1 = P.cW3[c1];
        const float bb0 = P.b2c[c0], bb1 = P.b2c[c1];
#pragma unroll
        for (int mt = 0; mt < 2; mt++) {
            short8 af[4];
#pragma unroll
            for (int kt = 0; kt < 4; kt++)
                af[kt] = *(const short8*)(&mc[(mt * 16 + lrow) * MSTR + kt * 32 + quad * 8]);
            f32x4 a0 = {0.f, 0.f, 0.f, 0.f}, a1 = {0.f, 0.f, 0.f, 0.f};
#pragma unroll
            for (int kt = 0; kt < 4; kt++) {
                a0 = __builtin_amdgcn_mfma_f32_16x16x32_bf16(af[kt], bf0[kt], a0, 0, 0, 0);
                a1 = __builtin_amdgcn_mfma_f32_16x16x32_bf16(af[kt], bf1[kt], a1, 0, 0, 0);
            }
#pragma unroll
            for (int r = 0; r < 4; r++) {
                float v0 = fsilu(a0[r] + bb0);
                float v1 = fsilu(a1[r] + bb1);
                float g = v0 * cw0 + v1 * cw1;
                g += __shfl_xor(g, 1, 64);
                g += __shfl_xor(g, 2, 64);
                g += __shfl_xor(g, 4, 64);
                g += __shfl_xor(g, 8, 64);
                if (lrow == 0) gpc[wv][mt * 16 + quad * 4 + r] = g;
            }
        }
    }

    // ---- GEMM2e: m2 = silu(m_h @ eW2 + b2); gate partials -> gpe; m2 in regs ----
    float m2s[2][8];
    {
        short8 bf0[4], bf1[4];
#pragma unroll
        for (int kt = 0; kt < 4; kt++) {
            bf0[kt] = *(const short8*)(P.W2t + c0 * 128 + kt * 32 + quad * 8);
            bf1[kt] = *(const short8*)(P.W2t + c1 * 128 + kt * 32 + quad * 8);
        }
        const float aw0 = P.aW[c0], aw1 = P.aW[c1];
        const float bb0 = P.b2e[c0], bb1 = P.b2e[c1];
#pragma unroll
        for (int mt = 0; mt < 2; mt++) {
            short8 af[4];
#pragma unroll
            for (int kt = 0; kt < 4; kt++)
                af[kt] = *(const short8*)(&mh[(mt * 16 + lrow) * MSTR + kt * 32 + quad * 8]);
            f32x4 a0 = {0.f, 0.f, 0.f, 0.f}, a1 = {0.f, 0.f, 0.f, 0.f};
#pragma unroll
            for (int kt = 0; kt < 4; kt++) {
                a0 = __builtin_amdgcn_mfma_f32_16x16x32_bf16(af[kt], bf0[kt], a0, 0, 0, 0);
                a1 = __builtin_amdgcn_mfma_f32_16x16x32_bf16(af[kt], bf1[kt], a1, 0, 0, 0);
            }
#pragma unroll
            for (int r = 0; r < 4; r++) {
                float v0 = fsilu(a0[r] + bb0);
                float v1 = fsilu(a1[r] + bb1);
                m2s[mt][r] = v0; m2s[mt][4 + r] = v1;
                float g = v0 * aw0 + v1 * aw1;
                g += __shfl_xor(g, 1, 64);
                g += __shfl_xor(g, 2, 64);
                g += __shfl_xor(g, 4, 64);
                g += __shfl_xor(g, 8, 64);
                if (lrow == 0) gpe[wv][mt * 16 + quad * 4 + r] = g;
            }
        }
    }
    __syncthreads();   // B2 (mh/mc reads done -> msg overlay safe; gpc/gpe complete)

    if (t < EPB) {
        sv_l[t]   = gpc[0][t] + gpc[1][t] + gpc[2][t] + gpc[3][t];
        gate_l[t] = fsigm(gpe[0][t] + gpe[1][t] + gpe[2][t] + gpe[3][t] + P.ab[0]);
    }
#pragma unroll
    for (int mt = 0; mt < 2; mt++)
#pragma unroll
        for (int r = 0; r < 4; r++) {
            const int erow = mt * 16 + quad * 4 + r;
            msg[erow * 132 + c0] = m2s[mt][r];
            msg[erow * 132 + c1] = m2s[mt][4 + r];
        }
    __syncthreads();   // B3 (last barrier)

    // ---- segmented reductions (dst-sorted); gate folded into h-scan ----
    if (t < 128) {
        const int col = t;
        float acc = 0.0f;
        int cur = dstl[0];
#pragma unroll 4
        for (int e = 0; e < EPB; e++) {
            const int d = dstl[e];
            if (d != cur) {
                atomAddF(&hne[(size_t)cur * 128 + col], acc);
                acc = 0.0f; cur = d;
            }
            acc += msg[e * 132 + col] * gate_l[e];
        }
        atomAddF(&hne[(size_t)cur * 128 + col], acc);
    } else if (t < 131) {
        const int ax = t - 128;
        float acc = 0.0f;
        int cur = dstl[0];
        for (int e = 0; e < EPB; e++) {
            const int d = dstl[e];
            if (d != cur) {
                atomAddF(&xne[cur * 3 + ax], acc);
                acc = 0.0f; cur = d;
            }
            acc += sv_l[e] * xdf[ax][e];
        }
        atomAddF(&xne[cur * 3 + ax], acc);
    }
}

// ---------------------------------------------------------------------------
// Node kernel: reads WS accumulators, writes d_out exactly once per element.
// ---------------------------------------------------------------------------
__global__ __launch_bounds__(256) void node_kernel(
    const float* __restrict__ h_lig, const float* __restrict__ zlig,
    const short* __restrict__ W1t, const float* __restrict__ b1v,
    const short* __restrict__ W2t, const float* __restrict__ b2v,
    const float* __restrict__ x_lig,
    const float* __restrict__ acc_h, const float* __restrict__ acc_x,
    float* __restrict__ h_out, float* __restrict__ x_out)
{
    __shared__ __align__(16) short f_lds[64 * FSTR];
    __shared__ __align__(16) short m_lds[64 * MSTR];
    const int t = threadIdx.x;
    const int nb = blockIdx.x * 64;

    {
        const int e = t >> 2, q = t & 3;
        const int node = nb + e;
        short* frow = &f_lds[e * FSTR + q * 32];
        if (node < 10000) {
            const float zi = frcp(zlig[node]);
            const float4* hp = (const float4*)(h_lig + (size_t)node * 128 + q * 32);
            const float4* np = (const float4*)(acc_h + (size_t)node * 128 + q * 32);
#pragma unroll
            for (int i = 0; i < 8; i++) {
                float4 v = hp[i];
                *(uint2*)(frow + i * 4) = make_uint2(pkbf(v.x, v.y), pkbf(v.z, v.w));
            }
#pragma unroll
            for (int i = 0; i < 8; i++) {
                float4 v = np[i];
                *(uint2*)(frow + 128 + i * 4) =
                    make_uint2(pkbf(v.x * zi, v.y * zi), pkbf(v.z * zi, v.w * zi));
            }
        } else {
            const uint2 zz = make_uint2(0, 0);
#pragma unroll
            for (int i = 0; i < 8; i++) {
                *(uint2*)(frow + i * 4) = zz;
                *(uint2*)(frow + 128 + i * 4) = zz;
            }
        }
    }
    __syncthreads();

    const int ln = t & 63, wv = t >> 6;
    const int lrow = ln & 15, quad = ln >> 4;
    const int c0 = wv * 32 + lrow, c1 = c0 + 16;

    {
        short8 bf0[8], bf1[8];
#pragma unroll
        for (int kt = 0; kt < 8; kt++) {
            bf0[kt] = *(const short8*)(W1t + c0 * 256 + kt * 32 + quad * 8);
            bf1[kt] = *(const short8*)(W1t + c1 * 256 + kt * 32 + quad * 8);
        }
        const float bb0 = b1v[c0], bb1 = b1v[c1];
#pragma unroll
        for (int mt = 0; mt < 4; mt++) {
            short8 af[8];
#pragma unroll
            for (int kt = 0; kt < 8; kt++)
                af[kt] = *(const short8*)(&f_lds[(mt * 16 + lrow) * FSTR + kt * 32 + quad * 8]);
            f32x4 a0 = {0.f, 0.f, 0.f, 0.f}, a1 = {0.f, 0.f, 0.f, 0.f};
#pragma unroll
            for (int kt = 0; kt < 8; kt++) {
                a0 = __builtin_amdgcn_mfma_f32_16x16x32_bf16(af[kt], bf0[kt], a0, 0, 0, 0);
                a1 = __builtin_amdgcn_mfma_f32_16x16x32_bf16(af[kt], bf1[kt], a1, 0, 0, 0);
            }
#pragma unroll
            for (int r = 0; r < 4; r++) {
                const int erow = mt * 16 + quad * 4 + r;
                m_lds[erow * MSTR + c0] = (short)f2bf(fsilu(a0[r] + bb0));
                m_lds[erow * MSTR + c1] = (short)f2bf(fsilu(a1[r] + bb1));
            }
        }
    }
    __syncthreads();

    {
        short8 bf0[4], bf1[4];
#pragma unroll
        for (int kt = 0; kt < 4; kt++) {
            bf0[kt] = *(const short8*)(W2t + c0 * 128 + kt * 32 + quad * 8);
            bf1[kt] = *(const short8*)(W2t + c1 * 128 + kt * 32 + quad * 8);
        }
        const float bb0 = b2v[c0], bb1 = b2v[c1];
#pragma unroll
        for (int mt = 0; mt < 4; mt++) {
            short8 af[4];
#pragma unroll
            for (int kt = 0; kt < 4; kt++)
                af[kt] = *(const short8*)(&m_lds[(mt * 16 + lrow) * MSTR + kt * 32 + quad * 8]);
            f32x4 a0 = {0.f, 0.f, 0.f, 0.f}, a1 = {0.f, 0.f, 0.f, 0.f};
#pragma unroll
            for (int kt = 0; kt < 4; kt++) {
                a0 = __builtin_amdgcn_mfma_f32_16x16x32_bf16(af[kt], bf0[kt], a0, 0, 0, 0);
                a1 = __builtin_amdgcn_mfma_f32_16x16x32_bf16(af[kt], bf1[kt], a1, 0, 0, 0);
            }
#pragma unroll
            for (int r = 0; r < 4; r++) {
                const int node = nb + mt * 16 + quad * 4 + r;
                if (node < 10000) {
                    h_out[(size_t)node * 128 + c0] = a0[r] + bb0 + h_lig[(size_t)node * 128 + c0];
                    h_out[(size_t)node * 128 + c1] = a1[r] + bb1 + h_lig[(size_t)node * 128 + c1];
                }
            }
        }
    }
    if (t < 64) {
        const int node = nb + t;
        if (node < 10000) {
            const float zi = frcp(zlig[node]);
#pragma unroll
            for (int i = 0; i < 3; i++)
                x_out[node * 3 + i] = x_lig[node * 3 + i] + acc_x[node * 3 + i] * zi;
        }
    }
}

extern "C" void kernel_launch(void* const* d_in, const int* in_sizes, int n_in,
                              void* d_out, int out_size, void* d_ws, size_t ws_size,
                              hipStream_t stream)
{
    (void)in_sizes; (void)n_in; (void)ws_size; (void)out_size;
    const float* h_lig  = (const float*)d_in[0];
    const float* h_kp   = (const float*)d_in[1];
    const float* x_lig  = (const float*)d_in[2];
    const float* x_kp   = (const float*)d_in[3];
    const float* z_lig  = (const float*)d_in[4];
    const float* ll_eW1 = (const float*)d_in[5];
    const float* ll_eb1 = (const float*)d_in[6];
    const float* ll_eW2 = (const float*)d_in[7];
    const float* ll_eb2 = (const float*)d_in[8];
    const float* ll_aW  = (const float*)d_in[9];
    const float* ll_ab  = (const float*)d_in[10];
    const float* ll_cW1 = (const float*)d_in[11];
    const float* ll_cb1 = (const float*)d_in[12];
    const float* ll_cW2 = (const float*)d_in[13];
    const float* ll_cb2 = (const float*)d_in[14];
    const float* ll_cW3 = (const float*)d_in[15];
    const float* kl_eW1 = (const float*)d_in[16];
    const float* kl_eb1 = (const float*)d_in[17];
    const float* kl_eW2 = (const float*)d_in[18];
    const float* kl_eb2 = (const float*)d_in[19];
    const float* kl_aW  = (const float*)d_in[20];
    const float* kl_ab  = (const float*)d_in[21];
    const float* kl_cW1 = (const float*)d_in[22];
    const float* kl_cb1 = (const float*)d_in[23];
    const float* kl_cW2 = (const float*)d_in[24];
    const float* kl_cb2 = (const float*)d_in[25];
    const float* kl_cW3 = (const float*)d_in[26];
    const float* n_W1   = (const float*)d_in[27];
    const float* n_b1   = (const float*)d_in[28];
    const float* n_W2   = (const float*)d_in[29];
    const float* n_b2   = (const float*)d_in[30];
    const int* ll_src = (const int*)d_in[31];
    const int* ll_dst = (const int*)d_in[32];
    const int* kl_src = (const int*)d_in[33];
    const int* kl_dst = (const int*)d_in[34];

    float* h_out = (float*)d_out;            // [10000,128]
    float* x_out = h_out + 1280000;          // [10000,3]

    // ws layout (bytes) — ~26.1 MB; accumulators live in WS (d_out write-once)
    char* wsc = (char*)d_ws;
    short* wsb    = (short*)wsc;                 //       0: weights (491,520 B)
    short* P_ll_s = (short*)(wsc +   491520);    // 5,120,000 B  [10000][256]
    short* P_ll_d = (short*)(wsc +  5611520);    // 5,120,000 B
    short* P_kl_s = (short*)(wsc + 10731520);    // 1,024,000 B  [2000][256]
    short* P_kl_d = (short*)(wsc + 11755520);    // 5,120,000 B
    int* ll_ssrc  = (int*)(wsc + 16875520);      // 1,280,000 B
    int* ll_sdst  = (int*)(wsc + 18155520);      // 1,280,000 B
    int* kl_ssrc  = (int*)(wsc + 19435520);      //   640,000 B
    int* kl_sdst  = (int*)(wsc + 20075520);      //   640,000 B
    int* hist     = (int*)(wsc + 20715520);      //    80,000 B (20000 ints)
    int* cursor   = (int*)(wsc + 20795520);      //    80,000 B
    float* hne    = (float*)(wsc + 20875520);    // 5,120,000 B  [10000][128]
    float* xne    = (float*)(wsc + 25995520);    //   120,000 B  [10000][3] -> end 26,115,520

    hipMemsetAsync(hne, 0, 5240000, stream);     // hne + xne (contiguous)
    hipMemsetAsync(hist, 0, 80000, stream);

    // A. weight transpose + histogram
    {
        PrepArgs pa;
        pa.src[0] = ll_eW1; pa.src[1] = ll_eW2; pa.src[2] = ll_cW1; pa.src[3] = ll_cW2;
        pa.src[4] = kl_eW1; pa.src[5] = kl_eW2; pa.src[6] = kl_cW1; pa.src[7] = kl_cW2;
        pa.src[8] = n_W1;   pa.src[9] = n_W2;
        prep_hist_kernel<<<2835, 256, 0, stream>>>(pa, wsb, ll_dst, kl_dst, hist);
    }
    // B. scan
    scan_kernel<<<2, 256, 0, stream>>>(hist, cursor);
    // C. scatter + projections fused
    {
        CArgs ca;
        ca.lls = ll_src; ca.lld = ll_dst; ca.kls = kl_src; ca.kld = kl_dst;
        ca.cursor = cursor;
        ca.ll_ssrc = ll_ssrc; ca.ll_sdst = ll_sdst;
        ca.kl_ssrc = kl_ssrc; ca.kl_sdst = kl_sdst;
        ca.d[0] = { h_lig, wsb + 0,      P_ll_s, ll_eb1, 10000, 0, 0,   0 };
        ca.d[1] = { h_lig, wsb + 49152,  P_ll_s, ll_cb1, 10000, 0, 128, 0 };
        ca.d[2] = { h_lig, wsb + 0,      P_ll_d, ll_eb1, 10000, 4, 0,   1 };
        ca.d[3] = { h_lig, wsb + 49152,  P_ll_d, ll_cb1, 10000, 4, 128, 1 };
        ca.d[4] = { h_kp,  wsb + 98304,  P_kl_s, kl_eb1,  2000, 0, 0,   0 };
        ca.d[5] = { h_kp,  wsb + 147456, P_kl_s, kl_cb1,  2000, 0, 128, 0 };
        ca.d[6] = { h_lig, wsb + 98304,  P_kl_d, kl_eb1, 10000, 4, 0,   1 };
        ca.d[7] = { h_lig, wsb + 147456, P_kl_d, kl_cb1, 10000, 4, 128, 1 };
        scatter_proj_kernel<<<1875 + 8 * 157, 256, 0, stream>>>(ca);
    }
    // D. edges (ll + kl in one launch), EPB=32
    {
        EdgePair ep;
        ep.split = 10000;
        ep.s[0] = { P_ll_s, P_ll_d, x_lig, x_lig, ll_ssrc, ll_sdst,
                    ll_eW1 + 256 * 128, ll_cW1 + 256 * 128,
                    wsb + 32768, wsb + 81920, ll_eb2, ll_cb2,
                    ll_aW, ll_ab, ll_cW3 };
        ep.s[1] = { P_kl_s, P_kl_d, x_kp, x_lig, kl_ssrc, kl_sdst,
                    kl_eW1 + 256 * 128, kl_cW1 + 256 * 128,
                    wsb + 131072, wsb + 180224, kl_eb2, kl_cb2,
                    kl_aW, kl_ab, kl_cW3 };
        edge_kernel<<<15000, 256, 0, stream>>>(ep, hne, xne);
    }
    // E. node MLP -> final outputs into d_out (write-once)
    node_kernel<<<157, 256, 0, stream>>>(
        h_lig, z_lig, wsb + 196608, n_b1, wsb + 229376, n_b2,
        x_lig, hne, xne, h_out, x_out);
}